// Round 5
// baseline (546.947 us; speedup 1.0000x reference)
//
#include <hip/hip_runtime.h>
#include <math.h>

#define NN 8192
#define DD 256
#define TOPK 64
#define CAP 96            // survivor capacity per row
#define CCAP 256          // candidate capacity for exact select
#define NEGVAL (-1000000000.0f)

typedef _Float16 f16;
typedef f16  f16x8 __attribute__((ext_vector_type(8)));
typedef float f32x4 __attribute__((ext_vector_type(4)));

// ---------------------------------------------------------------------------
// f32 NT GEMM for QKV projections (8192x256x256): C = A @ B^T + bias
// ---------------------------------------------------------------------------
__global__ __launch_bounds__(256)
void gemm_nt_f32(const float* __restrict__ A, const float* __restrict__ B,
                 float* __restrict__ C, int ldc, const float* __restrict__ bias)
{
  __shared__ float As[32][128];
  __shared__ float Bs[32][128];
  const int t  = threadIdx.x;
  const int tm = t & 15;
  const int tn = t >> 4;
  const int m0 = blockIdx.x * 128;
  const int n0 = blockIdx.y * 128;

  float acc[8][8];
#pragma unroll
  for (int i = 0; i < 8; ++i)
#pragma unroll
    for (int j = 0; j < 8; ++j) acc[i][j] = 0.0f;

  for (int k0 = 0; k0 < DD; k0 += 32) {
#pragma unroll
    for (int i = 0; i < 4; ++i) {
      int idx = t + i * 256;
      int row = idx >> 3;
      int c4  = (idx & 7) << 2;
      float4 av = *(const float4*)(A + (size_t)(m0 + row) * DD + k0 + c4);
      float4 bv = *(const float4*)(B + (size_t)(n0 + row) * DD + k0 + c4);
      As[c4 + 0][row] = av.x; As[c4 + 1][row] = av.y;
      As[c4 + 2][row] = av.z; As[c4 + 3][row] = av.w;
      Bs[c4 + 0][row] = bv.x; Bs[c4 + 1][row] = bv.y;
      Bs[c4 + 2][row] = bv.z; Bs[c4 + 3][row] = bv.w;
    }
    __syncthreads();
#pragma unroll
    for (int kk = 0; kk < 32; ++kk) {
      float a[8], b[8];
      *(float4*)&a[0] = *(const float4*)&As[kk][tm * 4];
      *(float4*)&a[4] = *(const float4*)&As[kk][64 + tm * 4];
      *(float4*)&b[0] = *(const float4*)&Bs[kk][tn * 4];
      *(float4*)&b[4] = *(const float4*)&Bs[kk][64 + tn * 4];
#pragma unroll
      for (int i = 0; i < 8; ++i)
#pragma unroll
        for (int j = 0; j < 8; ++j)
          acc[i][j] = fmaf(a[i], b[j], acc[i][j]);
    }
    __syncthreads();
  }

#pragma unroll
  for (int gi = 0; gi < 2; ++gi)
#pragma unroll
    for (int r = 0; r < 4; ++r) {
      const int grow = m0 + gi * 64 + tm * 4 + r;
#pragma unroll
      for (int gj = 0; gj < 2; ++gj) {
        const int gcol0 = n0 + gj * 64 + tn * 4;
        float v[4];
#pragma unroll
        for (int c = 0; c < 4; ++c)
          v[c] = acc[gi * 4 + r][gj * 4 + c] + (bias ? bias[gcol0 + c] : 0.0f);
        *(float4*)(C + (size_t)grow * ldc + gcol0) =
            make_float4(v[0], v[1], v[2], v[3]);
      }
    }
}

// ---------------------------------------------------------------------------
// Split Q,K (f32) into f16 hi/lo, K-dim-768 layout:
//   Qs[row] = [Qhi | Qhi | Qlo],  Ks[row] = [Khi | Klo | Khi]
// sum over 768 = Qhi*Khi + Qhi*Klo + Qlo*Khi (lo*lo dropped, ~2^-22)
// ---------------------------------------------------------------------------
__global__ __launch_bounds__(256)
void cvt_hilo(const float* __restrict__ Q, const float* __restrict__ Kf,
              f16* __restrict__ Qs, f16* __restrict__ Ks)
{
  const size_t i = (size_t)blockIdx.x * 256 + threadIdx.x;
  const int r = (int)(i >> 8);
  const int c = (int)(i & 255);
  float q = Q[i];
  f16 qh = (f16)q;
  f16 ql = (f16)(q - (float)qh);
  Qs[(size_t)r * 768 + c]       = qh;
  Qs[(size_t)r * 768 + 256 + c] = qh;
  Qs[(size_t)r * 768 + 512 + c] = ql;
  float k = Kf[i];
  f16 kh = (f16)k;
  f16 kl = (f16)(k - (float)kh);
  Ks[(size_t)r * 768 + c]       = kh;
  Ks[(size_t)r * 768 + 256 + c] = kl;
  Ks[(size_t)r * 768 + 512 + c] = kh;
}

// ---------------------------------------------------------------------------
// MFMA scores GEMM v3: 256x256 tile, BK=64, 8 waves (2x4), per-wave 128x64.
// Double-buffered LDS (128 KB) + minimal 2-phase pipeline (T3 minimum):
//   STAGE(buf^1, t+1) -> compute(buf) -> __syncthreads (vmcnt0+lgkm0+barrier)
// No XCD swizzle (R4: hurt fetch). No LDS swizzle (T2 null at 2-phase).
// ---------------------------------------------------------------------------
typedef __attribute__((address_space(1))) const void GV;
typedef __attribute__((address_space(3))) void LV;
__device__ __forceinline__ void gl_lds16(const void* g, void* l) {
  __builtin_amdgcn_global_load_lds((GV*)g, (LV*)l, 16, 0, 0);
}

__global__ __launch_bounds__(512, 2)
void gemm_scores_f16(const f16* __restrict__ Aq, const f16* __restrict__ Bk,
                     float* __restrict__ C, const float* __restrict__ temp,
                     int rowOff)
{
  __shared__ __align__(16) f16 As[2][256 * 64];   // 64 KB
  __shared__ __align__(16) f16 Bs[2][256 * 64];   // 64 KB
  const int t  = threadIdx.x;
  const int l  = t & 63;
  const int w  = t >> 6;        // wave 0..7
  const int wr = w >> 2;        // wave row half (0..1)   -> 128 rows
  const int wn = w & 3;         // wave col quarter (0..3) ->  64 cols
  const int m0 = blockIdx.x * 256;
  const int n0 = blockIdx.y * 256;
  const int fr = l & 15;        // fragment row/col within 16
  const int fg = l >> 4;        // fragment k-group / C row group

  f32x4 acc[8][4];
#pragma unroll
  for (int m = 0; m < 8; ++m)
#pragma unroll
    for (int n = 0; n < 4; ++n) acc[m][n] = (f32x4){0.f, 0.f, 0.f, 0.f};

  // stage one 256x64 K-tile of A and B into buffer `buf`
  auto stage = [&](int buf, int step) {
    const int k0 = step * 64;
#pragma unroll
    for (int i = 0; i < 4; ++i) {
      const int si  = i * 512 + t;        // 16B slot 0..2047
      const int row = si >> 3;            // 0..255
      const int sl  = (si & 7) * 8;       // k offset in f16
      // LDS dest: wave-uniform base; HW adds lane*16
      gl_lds16(Aq + (size_t)(m0 + row) * 768 + k0 + sl,
               &As[buf][(size_t)(i * 512 + w * 64) * 8]);
      gl_lds16(Bk + (size_t)(n0 + row) * 768 + k0 + sl,
               &Bs[buf][(size_t)(i * 512 + w * 64) * 8]);
    }
  };
  auto compute = [&](int buf) {
#pragma unroll
    for (int kk = 0; kk < 2; ++kk) {
      f16x8 af[8], bf[4];
#pragma unroll
      for (int m = 0; m < 8; ++m)
        af[m] = *(const f16x8*)&As[buf][(wr * 128 + m * 16 + fr) * 64 + kk * 32 + fg * 8];
#pragma unroll
      for (int n = 0; n < 4; ++n)
        bf[n] = *(const f16x8*)&Bs[buf][(wn * 64 + n * 16 + fr) * 64 + kk * 32 + fg * 8];
#pragma unroll
      for (int m = 0; m < 8; ++m)
#pragma unroll
        for (int n = 0; n < 4; ++n)
          acc[m][n] = __builtin_amdgcn_mfma_f32_16x16x32_f16(af[m], bf[n], acc[m][n], 0, 0, 0);
    }
  };

  // 12 K-steps (768/64), unrolled by 2 so buffer index is compile-time
  stage(0, 0);
  __syncthreads();
#pragma unroll 1
  for (int s2 = 0; s2 < 12; s2 += 2) {
    stage(1, s2 + 1);            // s2+1 <= 11 always
    compute(0);
    __syncthreads();             // vmcnt(0) lgkmcnt(0) barrier
    if (s2 + 2 < 12) stage(0, s2 + 2);
    compute(1);
    __syncthreads();
  }

  const float invts = 1.0f / (temp[0] * 16.0f);
#pragma unroll
  for (int m = 0; m < 8; ++m) {
#pragma unroll
    for (int j = 0; j < 4; ++j) {
      const int lrow = m0 + wr * 128 + m * 16 + fg * 4 + j;   // C/D row
      const int grow = rowOff + lrow;
#pragma unroll
      for (int n = 0; n < 4; ++n) {
        const int gcol = n0 + wn * 64 + n * 16 + fr;          // C/D col
        float x = acc[m][n][j] * invts;
        if (grow == gcol) x = NEGVAL;
        C[(size_t)lrow * NN + gcol] = x;
      }
    }
  }
}

// ---------------------------------------------------------------------------
// topk_softmax v2 (proven R3): row in registers, histogram select,
// exact 64th-largest among candidates, deterministic compaction.
// ---------------------------------------------------------------------------
__global__ __launch_bounds__(256)
void topk_softmax2(const float* __restrict__ Sc, int rowOff,
                   float* __restrict__ wts, int* __restrict__ idx,
                   int* __restrict__ cnt)
{
  __shared__ unsigned hist[256];
  __shared__ int      pfx[256];
  __shared__ float    candv[CCAP];
  __shared__ float    pb[CAP];
  __shared__ int      jb[CAP];
  __shared__ float    wmax[4], wsum[4];
  __shared__ int      sB, candn;
  __shared__ unsigned uT;

  const int t = threadIdx.x;
  const int l = t & 63;
  const int w = t >> 6;
  const int grow = rowOff + blockIdx.x;
  const float* srow = Sc + (size_t)blockIdx.x * NN;

  float v[32];
#pragma unroll
  for (int c = 0; c < 8; ++c) {
    float4 f = *(const float4*)(srow + ((size_t)c * 256 + t) * 4);
    v[c * 4 + 0] = f.x; v[c * 4 + 1] = f.y; v[c * 4 + 2] = f.z; v[c * 4 + 3] = f.w;
  }

  float lm = -3.0e38f;
#pragma unroll
  for (int r = 0; r < 32; ++r) lm = fmaxf(lm, v[r]);
#pragma unroll
  for (int off = 32; off; off >>= 1) lm = fmaxf(lm, __shfl_xor(lm, off));
  if (l == 0) wmax[w] = lm;
  __syncthreads();
  const float m = fmaxf(fmaxf(wmax[0], wmax[1]), fmaxf(wmax[2], wmax[3]));

  float lo = m - 2.5f;
  int B = -1;
  for (int iter = 0; iter < 8; ++iter) {
    hist[t] = 0u;
    __syncthreads();
    const float invw = 256.0f / (m - lo);
#pragma unroll
    for (int r = 0; r < 32; ++r) {
      float s = v[r];
      if (s >= lo) {
        int b = (int)((s - lo) * invw);
        b = (b > 255) ? 255 : b;
        atomicAdd(&hist[b], 1u);
      }
    }
    __syncthreads();
    for (int st = 1; st < 256; st <<= 1) {
      unsigned add = (t + st < 256) ? hist[t + st] : 0u;
      __syncthreads();
      hist[t] += add;
      __syncthreads();
    }
    if (hist[0] >= TOPK) {
      unsigned here = hist[t];
      unsigned nxt = (t == 255) ? 0u : hist[t + 1];
      if (here >= TOPK && nxt < TOPK) sB = t;
      __syncthreads();
      B = sB;
      break;
    }
    __syncthreads();
    lo = m - 2.5f * (float)(2 << iter);
  }
  if (B < 0) B = 0;

  if (t == 0) candn = 0;
  __syncthreads();
  {
    const float invw = 256.0f / (m - lo);
#pragma unroll
    for (int r = 0; r < 32; ++r) {
      float s = v[r];
      if (s >= lo) {
        int b = (int)((s - lo) * invw);
        b = (b > 255) ? 255 : b;
        if (b >= B) {
          int p = atomicAdd(&candn, 1);
          if (p < CCAP) candv[p] = s;
        }
      }
    }
  }
  __syncthreads();
  const int L = (candn < CCAP) ? candn : CCAP;

  if (t == 0) uT = 0xFFFFFFFFu;
  __syncthreads();
  for (int i = t; i < L; i += 256) {
    float vi = candv[i];
    int g = 0;
    for (int j = 0; j < L; ++j) g += (candv[j] > vi) ? 1 : 0;
    if (g <= TOPK - 1) {
      unsigned ub = __float_as_uint(vi);
      unsigned u = (ub & 0x80000000u) ? ~ub : (ub | 0x80000000u);
      atomicMin(&uT, u);
    }
  }
  __syncthreads();
  const unsigned uth = uT;
  const float T = __uint_as_float((uth & 0x80000000u) ? (uth & 0x7FFFFFFFu) : ~uth);

  int myc = 0;
#pragma unroll
  for (int r = 0; r < 32; ++r) myc += (v[r] >= T) ? 1 : 0;
  pfx[t] = myc;
  __syncthreads();
  for (int st = 1; st < 256; st <<= 1) {
    int add = (t >= st) ? pfx[t - st] : 0;
    __syncthreads();
    pfx[t] += add;
    __syncthreads();
  }
  int base = pfx[t] - myc;
  const int total = pfx[255];
#pragma unroll
  for (int r = 0; r < 32; ++r) {
    if (v[r] >= T) {
      if (base < CAP) {
        pb[base] = __expf(v[r] - m);
        jb[base] = ((r >> 2) * 256 + t) * 4 + (r & 3);
      }
      ++base;
    }
  }
  __syncthreads();
  const int L2 = (total < CAP) ? total : CAP;

  float ps = 0.0f;
  for (int i = t; i < L2; i += 256) ps += pb[i];
#pragma unroll
  for (int off = 32; off; off >>= 1) ps += __shfl_xor(ps, off);
  if (l == 0) wsum[w] = ps;
  __syncthreads();
  const float inv = 1.0f / (wsum[0] + wsum[1] + wsum[2] + wsum[3]);
  for (int i = t; i < L2; i += 256) {
    wts[(size_t)grow * CAP + i] = pb[i] * inv;
    idx[(size_t)grow * CAP + i] = jb[i];
  }
  if (t == 0) cnt[grow] = L2;
}

// ---------------------------------------------------------------------------
__global__ __launch_bounds__(256)
void sparse_av(const float* __restrict__ V, const float* __restrict__ wts,
               const int* __restrict__ idx, const int* __restrict__ cnt,
               float* __restrict__ out)
{
  __shared__ float wl[CAP];
  __shared__ int   jl[CAP];
  const int t = threadIdx.x;
  const int row = blockIdx.x;
  const int L = cnt[row];
  if (t < CAP && t < L) {
    wl[t] = wts[(size_t)row * CAP + t];
    jl[t] = idx[(size_t)row * CAP + t];
  }
  __syncthreads();
  float acc = 0.0f;
  for (int i = 0; i < L; ++i)
    acc = fmaf(wl[i], V[(size_t)jl[i] * DD + t], acc);
  out[(size_t)row * DD + t] = acc;
}

// ---------------------------------------------------------------------------
extern "C" void kernel_launch(void* const* d_in, const int* in_sizes, int n_in,
                              void* d_out, int out_size, void* d_ws, size_t ws_size,
                              hipStream_t stream)
{
  const float* X    = (const float*)d_in[0];
  const float* Wq   = (const float*)d_in[1];
  const float* bq   = (const float*)d_in[2];
  const float* Wk   = (const float*)d_in[3];
  const float* bk   = (const float*)d_in[4];
  const float* Wv   = (const float*)d_in[5];
  const float* bv   = (const float*)d_in[6];
  const float* temp = (const float*)d_in[7];
  float* out = (float*)d_out;
  float* ws  = (float*)d_ws;

  const size_t avail = ws_size / sizeof(float);

  const size_t szQK  = (size_t)NN * DD;
  const size_t szHL  = (size_t)NN * 768 / 2;
  const size_t szWts = (size_t)NN * CAP;
  const size_t szIdx = (size_t)NN * CAP;
  const size_t szCnt = NN;
  const size_t fixed = 2 * szQK + 2 * szHL + szWts + szIdx + szCnt;

  size_t o = 0;
  float* Kbuf = ws + o; o += szQK;
  float* Qbuf = ws + o; o += szQK;
  f16*   Qs   = (f16*)(ws + o); o += szHL;
  f16*   Ks   = (f16*)(ws + o); o += szHL;
  float* wts  = ws + o; o += szWts;
  int*   idxb = (int*)(ws + o); o += szIdx;
  int*   cntb = (int*)(ws + o); o += szCnt;

  if (avail <= fixed + (size_t)256 * NN) return;
  int CR = (int)(((avail - fixed) / NN) / 256) * 256;
  if (CR > NN) CR = NN;
  float* Sc = ws + o;

  dim3 blk(256);
  dim3 blk2(512);

  gemm_nt_f32<<<dim3(NN/128, DD/128), blk, 0, stream>>>(X, Wk, Kbuf, DD, bk);
  gemm_nt_f32<<<dim3(NN/128, DD/128), blk, 0, stream>>>(X, Wq, Qbuf, DD, bq);
  cvt_hilo<<<dim3((NN * DD) / 256), blk, 0, stream>>>(Qbuf, Kbuf, Qs, Ks);
  float* Vbuf = Qbuf;
  gemm_nt_f32<<<dim3(NN/128, DD/128), blk, 0, stream>>>(X, Wv, Vbuf, DD, bv);

  for (int r0 = 0; r0 < NN; r0 += CR) {
    const int rows = (NN - r0 < CR) ? (NN - r0) : CR;
    gemm_scores_f16<<<dim3(rows/256, NN/256), blk2, 0, stream>>>(
        Qs + (size_t)r0 * 768, Ks, Sc, temp, r0);
    topk_softmax2<<<dim3(rows), blk, 0, stream>>>(Sc, r0, wts, idxb, cntb);
  }

  sparse_av<<<dim3(NN), blk, 0, stream>>>(Vbuf, wts, idxb, cntb, out);
}

// Round 6
// 488.117 us; speedup vs baseline: 1.1205x; 1.1205x over previous
//
#include <hip/hip_runtime.h>
#include <math.h>

#define NN 8192
#define DD 256
#define TOPK 64
#define CAP 96            // survivor capacity per row
#define CCAP 256          // candidate capacity for exact select
#define NEGVAL (-1000000000.0f)

typedef _Float16 f16;
typedef f16  f16x8 __attribute__((ext_vector_type(8)));
typedef float f32x4 __attribute__((ext_vector_type(4)));

// ---------------------------------------------------------------------------
// f32 NT GEMM for QKV projections (8192x256x256): C = A @ B^T + bias
// ---------------------------------------------------------------------------
__global__ __launch_bounds__(256)
void gemm_nt_f32(const float* __restrict__ A, const float* __restrict__ B,
                 float* __restrict__ C, int ldc, const float* __restrict__ bias)
{
  __shared__ float As[32][128];
  __shared__ float Bs[32][128];
  const int t  = threadIdx.x;
  const int tm = t & 15;
  const int tn = t >> 4;
  const int m0 = blockIdx.x * 128;
  const int n0 = blockIdx.y * 128;

  float acc[8][8];
#pragma unroll
  for (int i = 0; i < 8; ++i)
#pragma unroll
    for (int j = 0; j < 8; ++j) acc[i][j] = 0.0f;

  for (int k0 = 0; k0 < DD; k0 += 32) {
#pragma unroll
    for (int i = 0; i < 4; ++i) {
      int idx = t + i * 256;
      int row = idx >> 3;
      int c4  = (idx & 7) << 2;
      float4 av = *(const float4*)(A + (size_t)(m0 + row) * DD + k0 + c4);
      float4 bv = *(const float4*)(B + (size_t)(n0 + row) * DD + k0 + c4);
      As[c4 + 0][row] = av.x; As[c4 + 1][row] = av.y;
      As[c4 + 2][row] = av.z; As[c4 + 3][row] = av.w;
      Bs[c4 + 0][row] = bv.x; Bs[c4 + 1][row] = bv.y;
      Bs[c4 + 2][row] = bv.z; Bs[c4 + 3][row] = bv.w;
    }
    __syncthreads();
#pragma unroll
    for (int kk = 0; kk < 32; ++kk) {
      float a[8], b[8];
      *(float4*)&a[0] = *(const float4*)&As[kk][tm * 4];
      *(float4*)&a[4] = *(const float4*)&As[kk][64 + tm * 4];
      *(float4*)&b[0] = *(const float4*)&Bs[kk][tn * 4];
      *(float4*)&b[4] = *(const float4*)&Bs[kk][64 + tn * 4];
#pragma unroll
      for (int i = 0; i < 8; ++i)
#pragma unroll
        for (int j = 0; j < 8; ++j)
          acc[i][j] = fmaf(a[i], b[j], acc[i][j]);
    }
    __syncthreads();
  }

#pragma unroll
  for (int gi = 0; gi < 2; ++gi)
#pragma unroll
    for (int r = 0; r < 4; ++r) {
      const int grow = m0 + gi * 64 + tm * 4 + r;
#pragma unroll
      for (int gj = 0; gj < 2; ++gj) {
        const int gcol0 = n0 + gj * 64 + tn * 4;
        float v[4];
#pragma unroll
        for (int c = 0; c < 4; ++c)
          v[c] = acc[gi * 4 + r][gj * 4 + c] + (bias ? bias[gcol0 + c] : 0.0f);
        *(float4*)(C + (size_t)grow * ldc + gcol0) =
            make_float4(v[0], v[1], v[2], v[3]);
      }
    }
}

// ---------------------------------------------------------------------------
// Split Q,K (f32) into f16 hi/lo, K-dim-768 layout:
//   Qs[row] = [Qhi | Qhi | Qlo],  Ks[row] = [Khi | Klo | Khi]
// sum over 768 = Qhi*Khi + Qhi*Klo + Qlo*Khi (lo*lo dropped, ~2^-22)
// ---------------------------------------------------------------------------
__global__ __launch_bounds__(256)
void cvt_hilo(const float* __restrict__ Q, const float* __restrict__ Kf,
              f16* __restrict__ Qs, f16* __restrict__ Ks)
{
  const size_t i = (size_t)blockIdx.x * 256 + threadIdx.x;
  const int r = (int)(i >> 8);
  const int c = (int)(i & 255);
  float q = Q[i];
  f16 qh = (f16)q;
  f16 ql = (f16)(q - (float)qh);
  Qs[(size_t)r * 768 + c]       = qh;
  Qs[(size_t)r * 768 + 256 + c] = qh;
  Qs[(size_t)r * 768 + 512 + c] = ql;
  float k = Kf[i];
  f16 kh = (f16)k;
  f16 kl = (f16)(k - (float)kh);
  Ks[(size_t)r * 768 + c]       = kh;
  Ks[(size_t)r * 768 + 256 + c] = kl;
  Ks[(size_t)r * 768 + 512 + c] = kh;
}

// ---------------------------------------------------------------------------
// MFMA scores GEMM (R3 structure, proven 151us/chunk) with ONE change:
// LDS-staged transpose epilogue -> full-128B-line coalesced C stores.
// No XCD swizzle (R4: fetch explosion). No LDS read swizzle (R4: no gain).
// ---------------------------------------------------------------------------
typedef __attribute__((address_space(1))) const void GV;
typedef __attribute__((address_space(3))) void LV;
__device__ __forceinline__ void gl_lds16(const void* g, void* l) {
  __builtin_amdgcn_global_load_lds((GV*)g, (LV*)l, 16, 0, 0);
}

__global__ __launch_bounds__(256)
void gemm_scores_f16(const f16* __restrict__ Aq, const f16* __restrict__ Bk,
                     float* __restrict__ C, const float* __restrict__ temp,
                     int rowOff)
{
  __shared__ __align__(16) char smem[32768];
  f16* As = (f16*)smem;                       // 128 rows x 64 f16 (16 KB)
  f16* Bs = (f16*)(smem + 16384);             // 128 rows x 64 f16 (16 KB)
  float (*Cs)[132] = (float (*)[132])smem;    // 32 x 132 f32 (16.9 KB), alias

  const int t  = threadIdx.x;
  const int l  = t & 63;
  const int w  = t >> 6;          // wave 0..3
  const int wr = w >> 1;          // wave row half
  const int wc = w & 1;           // wave col half
  const int m0 = blockIdx.x * 128;
  const int n0 = blockIdx.y * 128;

  f32x4 acc[4][4];
#pragma unroll
  for (int m = 0; m < 4; ++m)
#pragma unroll
    for (int n = 0; n < 4; ++n) acc[m][n] = (f32x4){0.f, 0.f, 0.f, 0.f};

  const int lr = l >> 3;          // staging: row within 8-row segment
  const int lk = (l & 7) * 8;     // staging: k offset (f16)
  const int fr = l & 15;          // fragment row/col
  const int fg = l >> 4;          // fragment k-group (0..3)

  for (int k0 = 0; k0 < 768; k0 += 64) {
    __syncthreads();
#pragma unroll
    for (int i = 0; i < 4; ++i) {
      const int seg = w * 4 + i;  // 0..15, rows seg*8..seg*8+7
      gl_lds16(Aq + (size_t)(m0 + seg * 8 + lr) * 768 + k0 + lk, &As[seg * 512]);
      gl_lds16(Bk + (size_t)(n0 + seg * 8 + lr) * 768 + k0 + lk, &Bs[seg * 512]);
    }
    __syncthreads();
#pragma unroll
    for (int kk = 0; kk < 2; ++kk) {
      f16x8 af[4], bf[4];
#pragma unroll
      for (int m = 0; m < 4; ++m)
        af[m] = *(const f16x8*)&As[(wr * 64 + m * 16 + fr) * 64 + kk * 32 + fg * 8];
#pragma unroll
      for (int n = 0; n < 4; ++n)
        bf[n] = *(const f16x8*)&Bs[(wc * 64 + n * 16 + fr) * 64 + kk * 32 + fg * 8];
#pragma unroll
      for (int m = 0; m < 4; ++m)
#pragma unroll
        for (int n = 0; n < 4; ++n)
          acc[m][n] = __builtin_amdgcn_mfma_f32_16x16x32_f16(af[m], bf[n], acc[m][n], 0, 0, 0);
    }
  }

  const float invts = 1.0f / (temp[0] * 16.0f);

  // LDS-transposed coalesced store: 4 passes of 32 rows x 128 cols.
  // Pass p holds C rows p*32..p*32+31; owning waves: wr == p>>1,
  // acc m in {(p&1)*2, (p&1)*2+1}. Row within pass = mm*16 + fg*4 + j.
#pragma unroll
  for (int p = 0; p < 4; ++p) {
    __syncthreads();               // previous pass read done / K-loop done
    if (wr == (p >> 1)) {
      const int h = p & 1;
#pragma unroll
      for (int mm = 0; mm < 2; ++mm) {
        const int m = h * 2 + mm;
#pragma unroll
        for (int n = 0; n < 4; ++n)
#pragma unroll
          for (int j = 0; j < 4; ++j)
            Cs[mm * 16 + fg * 4 + j][wc * 64 + n * 16 + fr] = acc[m][n][j] * invts;
      }
    }
    __syncthreads();
#pragma unroll
    for (int k = 0; k < 4; ++k) {
      const int c   = t + k * 256;          // 0..1023 float4 slots
      const int r32 = c >> 5;               // 0..31
      const int c4  = (c & 31) * 4;         // 0..124
      const int lrow = m0 + p * 32 + r32;   // row within Sc chunk
      float4 vv = *(const float4*)&Cs[r32][c4];
      const int dq = (rowOff + lrow) - (n0 + c4);
      if (dq >= 0 && dq < 4) ((float*)&vv)[dq] = NEGVAL;
      *(float4*)(C + (size_t)lrow * NN + n0 + c4) = vv;
    }
  }
}

// ---------------------------------------------------------------------------
// topk_softmax v2 (proven R3): row in registers, histogram select,
// exact 64th-largest among candidates, deterministic compaction.
// ---------------------------------------------------------------------------
__global__ __launch_bounds__(256)
void topk_softmax2(const float* __restrict__ Sc, int rowOff,
                   float* __restrict__ wts, int* __restrict__ idx,
                   int* __restrict__ cnt)
{
  __shared__ unsigned hist[256];
  __shared__ int      pfx[256];
  __shared__ float    candv[CCAP];
  __shared__ float    pb[CAP];
  __shared__ int      jb[CAP];
  __shared__ float    wmax[4], wsum[4];
  __shared__ int      sB, candn;
  __shared__ unsigned uT;

  const int t = threadIdx.x;
  const int l = t & 63;
  const int w = t >> 6;
  const int grow = rowOff + blockIdx.x;
  const float* srow = Sc + (size_t)blockIdx.x * NN;

  float v[32];
#pragma unroll
  for (int c = 0; c < 8; ++c) {
    float4 f = *(const float4*)(srow + ((size_t)c * 256 + t) * 4);
    v[c * 4 + 0] = f.x; v[c * 4 + 1] = f.y; v[c * 4 + 2] = f.z; v[c * 4 + 3] = f.w;
  }

  float lm = -3.0e38f;
#pragma unroll
  for (int r = 0; r < 32; ++r) lm = fmaxf(lm, v[r]);
#pragma unroll
  for (int off = 32; off; off >>= 1) lm = fmaxf(lm, __shfl_xor(lm, off));
  if (l == 0) wmax[w] = lm;
  __syncthreads();
  const float m = fmaxf(fmaxf(wmax[0], wmax[1]), fmaxf(wmax[2], wmax[3]));

  float lo = m - 2.5f;
  int B = -1;
  for (int iter = 0; iter < 8; ++iter) {
    hist[t] = 0u;
    __syncthreads();
    const float invw = 256.0f / (m - lo);
#pragma unroll
    for (int r = 0; r < 32; ++r) {
      float s = v[r];
      if (s >= lo) {
        int b = (int)((s - lo) * invw);
        b = (b > 255) ? 255 : b;
        atomicAdd(&hist[b], 1u);
      }
    }
    __syncthreads();
    for (int st = 1; st < 256; st <<= 1) {
      unsigned add = (t + st < 256) ? hist[t + st] : 0u;
      __syncthreads();
      hist[t] += add;
      __syncthreads();
    }
    if (hist[0] >= TOPK) {
      unsigned here = hist[t];
      unsigned nxt = (t == 255) ? 0u : hist[t + 1];
      if (here >= TOPK && nxt < TOPK) sB = t;
      __syncthreads();
      B = sB;
      break;
    }
    __syncthreads();
    lo = m - 2.5f * (float)(2 << iter);
  }
  if (B < 0) B = 0;

  if (t == 0) candn = 0;
  __syncthreads();
  {
    const float invw = 256.0f / (m - lo);
#pragma unroll
    for (int r = 0; r < 32; ++r) {
      float s = v[r];
      if (s >= lo) {
        int b = (int)((s - lo) * invw);
        b = (b > 255) ? 255 : b;
        if (b >= B) {
          int p = atomicAdd(&candn, 1);
          if (p < CCAP) candv[p] = s;
        }
      }
    }
  }
  __syncthreads();
  const int L = (candn < CCAP) ? candn : CCAP;

  if (t == 0) uT = 0xFFFFFFFFu;
  __syncthreads();
  for (int i = t; i < L; i += 256) {
    float vi = candv[i];
    int g = 0;
    for (int j = 0; j < L; ++j) g += (candv[j] > vi) ? 1 : 0;
    if (g <= TOPK - 1) {
      unsigned ub = __float_as_uint(vi);
      unsigned u = (ub & 0x80000000u) ? ~ub : (ub | 0x80000000u);
      atomicMin(&uT, u);
    }
  }
  __syncthreads();
  const unsigned uth = uT;
  const float T = __uint_as_float((uth & 0x80000000u) ? (uth & 0x7FFFFFFFu) : ~uth);

  int myc = 0;
#pragma unroll
  for (int r = 0; r < 32; ++r) myc += (v[r] >= T) ? 1 : 0;
  pfx[t] = myc;
  __syncthreads();
  for (int st = 1; st < 256; st <<= 1) {
    int add = (t >= st) ? pfx[t - st] : 0;
    __syncthreads();
    pfx[t] += add;
    __syncthreads();
  }
  int base = pfx[t] - myc;
  const int total = pfx[255];
#pragma unroll
  for (int r = 0; r < 32; ++r) {
    if (v[r] >= T) {
      if (base < CAP) {
        pb[base] = __expf(v[r] - m);
        jb[base] = ((r >> 2) * 256 + t) * 4 + (r & 3);
      }
      ++base;
    }
  }
  __syncthreads();
  const int L2 = (total < CAP) ? total : CAP;

  float ps = 0.0f;
  for (int i = t; i < L2; i += 256) ps += pb[i];
#pragma unroll
  for (int off = 32; off; off >>= 1) ps += __shfl_xor(ps, off);
  if (l == 0) wsum[w] = ps;
  __syncthreads();
  const float inv = 1.0f / (wsum[0] + wsum[1] + wsum[2] + wsum[3]);
  for (int i = t; i < L2; i += 256) {
    wts[(size_t)grow * CAP + i] = pb[i] * inv;
    idx[(size_t)grow * CAP + i] = jb[i];
  }
  if (t == 0) cnt[grow] = L2;
}

// ---------------------------------------------------------------------------
__global__ __launch_bounds__(256)
void sparse_av(const float* __restrict__ V, const float* __restrict__ wts,
               const int* __restrict__ idx, const int* __restrict__ cnt,
               float* __restrict__ out)
{
  __shared__ float wl[CAP];
  __shared__ int   jl[CAP];
  const int t = threadIdx.x;
  const int row = blockIdx.x;
  const int L = cnt[row];
  if (t < CAP && t < L) {
    wl[t] = wts[(size_t)row * CAP + t];
    jl[t] = idx[(size_t)row * CAP + t];
  }
  __syncthreads();
  float acc = 0.0f;
  for (int i = 0; i < L; ++i)
    acc = fmaf(wl[i], V[(size_t)jl[i] * DD + t], acc);
  out[(size_t)row * DD + t] = acc;
}

// ---------------------------------------------------------------------------
extern "C" void kernel_launch(void* const* d_in, const int* in_sizes, int n_in,
                              void* d_out, int out_size, void* d_ws, size_t ws_size,
                              hipStream_t stream)
{
  const float* X    = (const float*)d_in[0];
  const float* Wq   = (const float*)d_in[1];
  const float* bq   = (const float*)d_in[2];
  const float* Wk   = (const float*)d_in[3];
  const float* bk   = (const float*)d_in[4];
  const float* Wv   = (const float*)d_in[5];
  const float* bv   = (const float*)d_in[6];
  const float* temp = (const float*)d_in[7];
  float* out = (float*)d_out;
  float* ws  = (float*)d_ws;

  const size_t avail = ws_size / sizeof(float);

  const size_t szQK  = (size_t)NN * DD;
  const size_t szHL  = (size_t)NN * 768 / 2;
  const size_t szWts = (size_t)NN * CAP;
  const size_t szIdx = (size_t)NN * CAP;
  const size_t szCnt = NN;
  const size_t fixed = 2 * szQK + 2 * szHL + szWts + szIdx + szCnt;

  size_t o = 0;
  float* Kbuf = ws + o; o += szQK;
  float* Qbuf = ws + o; o += szQK;
  f16*   Qs   = (f16*)(ws + o); o += szHL;
  f16*   Ks   = (f16*)(ws + o); o += szHL;
  float* wts  = ws + o; o += szWts;
  int*   idxb = (int*)(ws + o); o += szIdx;
  int*   cntb = (int*)(ws + o); o += szCnt;

  if (avail <= fixed + (size_t)128 * NN) return;
  int CR = (int)(((avail - fixed) / NN) / 128) * 128;
  if (CR > NN) CR = NN;
  float* Sc = ws + o;

  dim3 blk(256);

  gemm_nt_f32<<<dim3(NN/128, DD/128), blk, 0, stream>>>(X, Wk, Kbuf, DD, bk);
  gemm_nt_f32<<<dim3(NN/128, DD/128), blk, 0, stream>>>(X, Wq, Qbuf, DD, bq);
  cvt_hilo<<<dim3((NN * DD) / 256), blk, 0, stream>>>(Qbuf, Kbuf, Qs, Ks);
  float* Vbuf = Qbuf;
  gemm_nt_f32<<<dim3(NN/128, DD/128), blk, 0, stream>>>(X, Wv, Vbuf, DD, bv);

  for (int r0 = 0; r0 < NN; r0 += CR) {
    const int rows = (NN - r0 < CR) ? (NN - r0) : CR;
    gemm_scores_f16<<<dim3(rows/128, NN/128), blk, 0, stream>>>(
        Qs + (size_t)r0 * 768, Ks, Sc, temp, r0);
    topk_softmax2<<<dim3(rows), blk, 0, stream>>>(Sc, r0, wts, idxb, cntb);
  }

  sparse_av<<<dim3(NN), blk, 0, stream>>>(Vbuf, wts, idxb, cntb, out);
}

// Round 7
// 451.384 us; speedup vs baseline: 1.2117x; 1.0814x over previous
//
#include <hip/hip_runtime.h>
#include <math.h>

#define NN 8192
#define DD 256
#define TOPK 64
#define CAP 96            // survivor capacity per row
#define CCAP 256          // candidate capacity for exact select
#define CRMAX 2048        // score-chunk rows: Sc = 64 MB -> L3-resident
#define NEGVAL (-1000000000.0f)

typedef _Float16 f16;
typedef f16  f16x8 __attribute__((ext_vector_type(8)));
typedef float f32x4 __attribute__((ext_vector_type(4)));

// ---------------------------------------------------------------------------
// f32 NT GEMM for QKV projections (8192x256x256): C = A @ B^T + bias
// ---------------------------------------------------------------------------
__global__ __launch_bounds__(256)
void gemm_nt_f32(const float* __restrict__ A, const float* __restrict__ B,
                 float* __restrict__ C, int ldc, const float* __restrict__ bias)
{
  __shared__ float As[32][128];
  __shared__ float Bs[32][128];
  const int t  = threadIdx.x;
  const int tm = t & 15;
  const int tn = t >> 4;
  const int m0 = blockIdx.x * 128;
  const int n0 = blockIdx.y * 128;

  float acc[8][8];
#pragma unroll
  for (int i = 0; i < 8; ++i)
#pragma unroll
    for (int j = 0; j < 8; ++j) acc[i][j] = 0.0f;

  for (int k0 = 0; k0 < DD; k0 += 32) {
#pragma unroll
    for (int i = 0; i < 4; ++i) {
      int idx = t + i * 256;
      int row = idx >> 3;
      int c4  = (idx & 7) << 2;
      float4 av = *(const float4*)(A + (size_t)(m0 + row) * DD + k0 + c4);
      float4 bv = *(const float4*)(B + (size_t)(n0 + row) * DD + k0 + c4);
      As[c4 + 0][row] = av.x; As[c4 + 1][row] = av.y;
      As[c4 + 2][row] = av.z; As[c4 + 3][row] = av.w;
      Bs[c4 + 0][row] = bv.x; Bs[c4 + 1][row] = bv.y;
      Bs[c4 + 2][row] = bv.z; Bs[c4 + 3][row] = bv.w;
    }
    __syncthreads();
#pragma unroll
    for (int kk = 0; kk < 32; ++kk) {
      float a[8], b[8];
      *(float4*)&a[0] = *(const float4*)&As[kk][tm * 4];
      *(float4*)&a[4] = *(const float4*)&As[kk][64 + tm * 4];
      *(float4*)&b[0] = *(const float4*)&Bs[kk][tn * 4];
      *(float4*)&b[4] = *(const float4*)&Bs[kk][64 + tn * 4];
#pragma unroll
      for (int i = 0; i < 8; ++i)
#pragma unroll
        for (int j = 0; j < 8; ++j)
          acc[i][j] = fmaf(a[i], b[j], acc[i][j]);
    }
    __syncthreads();
  }

#pragma unroll
  for (int gi = 0; gi < 2; ++gi)
#pragma unroll
    for (int r = 0; r < 4; ++r) {
      const int grow = m0 + gi * 64 + tm * 4 + r;
#pragma unroll
      for (int gj = 0; gj < 2; ++gj) {
        const int gcol0 = n0 + gj * 64 + tn * 4;
        float v[4];
#pragma unroll
        for (int c = 0; c < 4; ++c)
          v[c] = acc[gi * 4 + r][gj * 4 + c] + (bias ? bias[gcol0 + c] : 0.0f);
        *(float4*)(C + (size_t)grow * ldc + gcol0) =
            make_float4(v[0], v[1], v[2], v[3]);
      }
    }
}

// ---------------------------------------------------------------------------
// Split Q,K (f32) into f16 hi/lo, K-dim-768 layout:
//   Qs[row] = [Qhi | Qhi | Qlo],  Ks[row] = [Khi | Klo | Khi]
// sum over 768 = Qhi*Khi + Qhi*Klo + Qlo*Khi (lo*lo dropped, ~2^-22)
// ---------------------------------------------------------------------------
__global__ __launch_bounds__(256)
void cvt_hilo(const float* __restrict__ Q, const float* __restrict__ Kf,
              f16* __restrict__ Qs, f16* __restrict__ Ks)
{
  const size_t i = (size_t)blockIdx.x * 256 + threadIdx.x;
  const int r = (int)(i >> 8);
  const int c = (int)(i & 255);
  float q = Q[i];
  f16 qh = (f16)q;
  f16 ql = (f16)(q - (float)qh);
  Qs[(size_t)r * 768 + c]       = qh;
  Qs[(size_t)r * 768 + 256 + c] = qh;
  Qs[(size_t)r * 768 + 512 + c] = ql;
  float k = Kf[i];
  f16 kh = (f16)k;
  f16 kl = (f16)(k - (float)kh);
  Ks[(size_t)r * 768 + c]       = kh;
  Ks[(size_t)r * 768 + 256 + c] = kl;
  Ks[(size_t)r * 768 + 512 + c] = kh;
}

// ---------------------------------------------------------------------------
// MFMA scores GEMM — R3's proven version (151us/chunk @CR=4096), unchanged:
// 128x128 tile, BK=64, 4 waves, global_load_lds staging, direct C store.
// ---------------------------------------------------------------------------
typedef __attribute__((address_space(1))) const void GV;
typedef __attribute__((address_space(3))) void LV;
__device__ __forceinline__ void gl_lds16(const void* g, void* l) {
  __builtin_amdgcn_global_load_lds((GV*)g, (LV*)l, 16, 0, 0);
}

__global__ __launch_bounds__(256)
void gemm_scores_f16(const f16* __restrict__ Aq, const f16* __restrict__ Bk,
                     float* __restrict__ C, const float* __restrict__ temp,
                     int rowOff)
{
  __shared__ __align__(16) f16 As[128 * 64];
  __shared__ __align__(16) f16 Bs[128 * 64];
  const int t  = threadIdx.x;
  const int l  = t & 63;
  const int w  = t >> 6;          // wave 0..3
  const int wr = w >> 1;          // wave row quadrant
  const int wc = w & 1;           // wave col quadrant
  const int m0 = blockIdx.x * 128;
  const int n0 = blockIdx.y * 128;

  f32x4 acc[4][4];
#pragma unroll
  for (int m = 0; m < 4; ++m)
#pragma unroll
    for (int n = 0; n < 4; ++n) acc[m][n] = (f32x4){0.f, 0.f, 0.f, 0.f};

  const int lr = l >> 3;          // staging: row within 8-row segment
  const int lk = (l & 7) * 8;     // staging: k offset (f16)
  const int fr = l & 15;          // fragment row/col
  const int fg = l >> 4;          // fragment k-group (0..3)

  for (int k0 = 0; k0 < 768; k0 += 64) {
    __syncthreads();
#pragma unroll
    for (int i = 0; i < 4; ++i) {
      const int seg = w * 4 + i;  // 0..15, rows seg*8..seg*8+7
      gl_lds16(Aq + (size_t)(m0 + seg * 8 + lr) * 768 + k0 + lk, &As[seg * 512]);
      gl_lds16(Bk + (size_t)(n0 + seg * 8 + lr) * 768 + k0 + lk, &Bs[seg * 512]);
    }
    __syncthreads();
#pragma unroll
    for (int kk = 0; kk < 2; ++kk) {
      f16x8 af[4], bf[4];
#pragma unroll
      for (int m = 0; m < 4; ++m)
        af[m] = *(const f16x8*)&As[(wr * 64 + m * 16 + fr) * 64 + kk * 32 + fg * 8];
#pragma unroll
      for (int n = 0; n < 4; ++n)
        bf[n] = *(const f16x8*)&Bs[(wc * 64 + n * 16 + fr) * 64 + kk * 32 + fg * 8];
#pragma unroll
      for (int m = 0; m < 4; ++m)
#pragma unroll
        for (int n = 0; n < 4; ++n)
          acc[m][n] = __builtin_amdgcn_mfma_f32_16x16x32_f16(af[m], bf[n], acc[m][n], 0, 0, 0);
    }
  }

  const float invts = 1.0f / (temp[0] * 16.0f);
#pragma unroll
  for (int m = 0; m < 4; ++m)
#pragma unroll
    for (int n = 0; n < 4; ++n) {
      const int gcol = n0 + wc * 64 + n * 16 + fr;    // C/D: col = lane&15
#pragma unroll
      for (int j = 0; j < 4; ++j) {                   // row = (lane>>4)*4 + j
        const int lrow = m0 + wr * 64 + m * 16 + fg * 4 + j;
        float x = acc[m][n][j] * invts;
        if (rowOff + lrow == gcol) x = NEGVAL;
        C[(size_t)lrow * NN + gcol] = x;
      }
    }
}

// ---------------------------------------------------------------------------
// topk_softmax v2 (proven R3): row in registers, histogram select,
// exact 64th-largest among candidates, deterministic compaction.
// ---------------------------------------------------------------------------
__global__ __launch_bounds__(256)
void topk_softmax2(const float* __restrict__ Sc, int rowOff,
                   float* __restrict__ wts, int* __restrict__ idx,
                   int* __restrict__ cnt)
{
  __shared__ unsigned hist[256];
  __shared__ int      pfx[256];
  __shared__ float    candv[CCAP];
  __shared__ float    pb[CAP];
  __shared__ int      jb[CAP];
  __shared__ float    wmax[4], wsum[4];
  __shared__ int      sB, candn;
  __shared__ unsigned uT;

  const int t = threadIdx.x;
  const int l = t & 63;
  const int w = t >> 6;
  const int grow = rowOff + blockIdx.x;
  const float* srow = Sc + (size_t)blockIdx.x * NN;

  float v[32];
#pragma unroll
  for (int c = 0; c < 8; ++c) {
    float4 f = *(const float4*)(srow + ((size_t)c * 256 + t) * 4);
    v[c * 4 + 0] = f.x; v[c * 4 + 1] = f.y; v[c * 4 + 2] = f.z; v[c * 4 + 3] = f.w;
  }

  float lm = -3.0e38f;
#pragma unroll
  for (int r = 0; r < 32; ++r) lm = fmaxf(lm, v[r]);
#pragma unroll
  for (int off = 32; off; off >>= 1) lm = fmaxf(lm, __shfl_xor(lm, off));
  if (l == 0) wmax[w] = lm;
  __syncthreads();
  const float m = fmaxf(fmaxf(wmax[0], wmax[1]), fmaxf(wmax[2], wmax[3]));

  float lo = m - 2.5f;
  int B = -1;
  for (int iter = 0; iter < 8; ++iter) {
    hist[t] = 0u;
    __syncthreads();
    const float invw = 256.0f / (m - lo);
#pragma unroll
    for (int r = 0; r < 32; ++r) {
      float s = v[r];
      if (s >= lo) {
        int b = (int)((s - lo) * invw);
        b = (b > 255) ? 255 : b;
        atomicAdd(&hist[b], 1u);
      }
    }
    __syncthreads();
    for (int st = 1; st < 256; st <<= 1) {
      unsigned add = (t + st < 256) ? hist[t + st] : 0u;
      __syncthreads();
      hist[t] += add;
      __syncthreads();
    }
    if (hist[0] >= TOPK) {
      unsigned here = hist[t];
      unsigned nxt = (t == 255) ? 0u : hist[t + 1];
      if (here >= TOPK && nxt < TOPK) sB = t;
      __syncthreads();
      B = sB;
      break;
    }
    __syncthreads();
    lo = m - 2.5f * (float)(2 << iter);
  }
  if (B < 0) B = 0;

  if (t == 0) candn = 0;
  __syncthreads();
  {
    const float invw = 256.0f / (m - lo);
#pragma unroll
    for (int r = 0; r < 32; ++r) {
      float s = v[r];
      if (s >= lo) {
        int b = (int)((s - lo) * invw);
        b = (b > 255) ? 255 : b;
        if (b >= B) {
          int p = atomicAdd(&candn, 1);
          if (p < CCAP) candv[p] = s;
        }
      }
    }
  }
  __syncthreads();
  const int L = (candn < CCAP) ? candn : CCAP;

  if (t == 0) uT = 0xFFFFFFFFu;
  __syncthreads();
  for (int i = t; i < L; i += 256) {
    float vi = candv[i];
    int g = 0;
    for (int j = 0; j < L; ++j) g += (candv[j] > vi) ? 1 : 0;
    if (g <= TOPK - 1) {
      unsigned ub = __float_as_uint(vi);
      unsigned u = (ub & 0x80000000u) ? ~ub : (ub | 0x80000000u);
      atomicMin(&uT, u);
    }
  }
  __syncthreads();
  const unsigned uth = uT;
  const float T = __uint_as_float((uth & 0x80000000u) ? (uth & 0x7FFFFFFFu) : ~uth);

  int myc = 0;
#pragma unroll
  for (int r = 0; r < 32; ++r) myc += (v[r] >= T) ? 1 : 0;
  pfx[t] = myc;
  __syncthreads();
  for (int st = 1; st < 256; st <<= 1) {
    int add = (t >= st) ? pfx[t - st] : 0;
    __syncthreads();
    pfx[t] += add;
    __syncthreads();
  }
  int base = pfx[t] - myc;
  const int total = pfx[255];
#pragma unroll
  for (int r = 0; r < 32; ++r) {
    if (v[r] >= T) {
      if (base < CAP) {
        pb[base] = __expf(v[r] - m);
        jb[base] = ((r >> 2) * 256 + t) * 4 + (r & 3);
      }
      ++base;
    }
  }
  __syncthreads();
  const int L2 = (total < CAP) ? total : CAP;

  float ps = 0.0f;
  for (int i = t; i < L2; i += 256) ps += pb[i];
#pragma unroll
  for (int off = 32; off; off >>= 1) ps += __shfl_xor(ps, off);
  if (l == 0) wsum[w] = ps;
  __syncthreads();
  const float inv = 1.0f / (wsum[0] + wsum[1] + wsum[2] + wsum[3]);
  for (int i = t; i < L2; i += 256) {
    wts[(size_t)grow * CAP + i] = pb[i] * inv;
    idx[(size_t)grow * CAP + i] = jb[i];
  }
  if (t == 0) cnt[grow] = L2;
}

// ---------------------------------------------------------------------------
__global__ __launch_bounds__(256)
void sparse_av(const float* __restrict__ V, const float* __restrict__ wts,
               const int* __restrict__ idx, const int* __restrict__ cnt,
               float* __restrict__ out)
{
  __shared__ float wl[CAP];
  __shared__ int   jl[CAP];
  const int t = threadIdx.x;
  const int row = blockIdx.x;
  const int L = cnt[row];
  if (t < CAP && t < L) {
    wl[t] = wts[(size_t)row * CAP + t];
    jl[t] = idx[(size_t)row * CAP + t];
  }
  __syncthreads();
  float acc = 0.0f;
  for (int i = 0; i < L; ++i)
    acc = fmaf(wl[i], V[(size_t)jl[i] * DD + t], acc);
  out[(size_t)row * DD + t] = acc;
}

// ---------------------------------------------------------------------------
extern "C" void kernel_launch(void* const* d_in, const int* in_sizes, int n_in,
                              void* d_out, int out_size, void* d_ws, size_t ws_size,
                              hipStream_t stream)
{
  const float* X    = (const float*)d_in[0];
  const float* Wq   = (const float*)d_in[1];
  const float* bq   = (const float*)d_in[2];
  const float* Wk   = (const float*)d_in[3];
  const float* bk   = (const float*)d_in[4];
  const float* Wv   = (const float*)d_in[5];
  const float* bv   = (const float*)d_in[6];
  const float* temp = (const float*)d_in[7];
  float* out = (float*)d_out;
  float* ws  = (float*)d_ws;

  const size_t avail = ws_size / sizeof(float);

  const size_t szQK  = (size_t)NN * DD;
  const size_t szHL  = (size_t)NN * 768 / 2;
  const size_t szWts = (size_t)NN * CAP;
  const size_t szIdx = (size_t)NN * CAP;
  const size_t szCnt = NN;
  const size_t fixed = 2 * szQK + 2 * szHL + szWts + szIdx + szCnt;

  size_t o = 0;
  float* Kbuf = ws + o; o += szQK;
  float* Qbuf = ws + o; o += szQK;
  f16*   Qs   = (f16*)(ws + o); o += szHL;
  f16*   Ks   = (f16*)(ws + o); o += szHL;
  float* wts  = ws + o; o += szWts;
  int*   idxb = (int*)(ws + o); o += szIdx;
  int*   cntb = (int*)(ws + o); o += szCnt;

  if (avail <= fixed + (size_t)128 * NN) return;
  int CR = (int)(((avail - fixed) / NN) / 128) * 128;
  if (CR > CRMAX) CR = CRMAX;       // 64 MB chunk: write->read->overwrite
  if (CR > NN) CR = NN;             // cycle stays L3-resident
  float* Sc = ws + o;

  dim3 blk(256);

  gemm_nt_f32<<<dim3(NN/128, DD/128), blk, 0, stream>>>(X, Wk, Kbuf, DD, bk);
  gemm_nt_f32<<<dim3(NN/128, DD/128), blk, 0, stream>>>(X, Wq, Qbuf, DD, bq);
  cvt_hilo<<<dim3((NN * DD) / 256), blk, 0, stream>>>(Qbuf, Kbuf, Qs, Ks);
  float* Vbuf = Qbuf;
  gemm_nt_f32<<<dim3(NN/128, DD/128), blk, 0, stream>>>(X, Wv, Vbuf, DD, bv);

  for (int r0 = 0; r0 < NN; r0 += CR) {
    const int rows = (NN - r0 < CR) ? (NN - r0) : CR;
    gemm_scores_f16<<<dim3(rows/128, NN/128), blk, 0, stream>>>(
        Qs + (size_t)r0 * 768, Ks, Sc, temp, r0);
    topk_softmax2<<<dim3(rows), blk, 0, stream>>>(Sc, r0, wts, idxb, cntb);
  }

  sparse_av<<<dim3(NN), blk, 0, stream>>>(Vbuf, wts, idxb, cntb, out);
}

// Round 8
// 391.003 us; speedup vs baseline: 1.3988x; 1.1544x over previous
//
#include <hip/hip_runtime.h>
#include <math.h>

#define NN 8192
#define DD 256
#define TOPK 64
#define CAP 96            // survivor capacity per row
#define CCAP 256          // candidate capacity for exact select
#define CRMAX 2048        // score-chunk rows: Sc = 64 MB -> L3-resident
#define NEGVAL (-1000000000.0f)

typedef _Float16 f16;
typedef f16  f16x4 __attribute__((ext_vector_type(4)));
typedef f16  f16x8 __attribute__((ext_vector_type(8)));
typedef float f32x4 __attribute__((ext_vector_type(4)));

// ---------------------------------------------------------------------------
// Fused QKV projection: one launch, grid (64, 6).
//   sel = blockIdx.y>>1 : 0->Q, 1->K, 2->V ;  n0 = (blockIdx.y&1)*128
// Q,K are written DIRECTLY as f16 hi/lo in the K-dim-768 score layout:
//   Qs[row] = [Qhi | Qhi | Qlo],  Ks[row] = [Khi | Klo | Khi]
// V is written f32. Same fmaf accumulation order as the proven R2 kernel ->
// bitwise-identical projections.
// ---------------------------------------------------------------------------
__global__ __launch_bounds__(256)
void gemm_qkv(const float* __restrict__ X,
              const float* __restrict__ Wq, const float* __restrict__ bq,
              const float* __restrict__ Wk, const float* __restrict__ bk,
              const float* __restrict__ Wv, const float* __restrict__ bv,
              f16* __restrict__ Qs, f16* __restrict__ Ks,
              float* __restrict__ Vf)
{
  __shared__ float As[32][128];
  __shared__ float Bs[32][128];
  const int t  = threadIdx.x;
  const int tm = t & 15;
  const int tn = t >> 4;
  const int m0 = blockIdx.x * 128;
  const int sel = blockIdx.y >> 1;
  const int n0  = (blockIdx.y & 1) * 128;
  const float* B    = (sel == 0) ? Wq : (sel == 1) ? Wk : Wv;
  const float* bias = (sel == 0) ? bq : (sel == 1) ? bk : bv;

  float acc[8][8];
#pragma unroll
  for (int i = 0; i < 8; ++i)
#pragma unroll
    for (int j = 0; j < 8; ++j) acc[i][j] = 0.0f;

  for (int k0 = 0; k0 < DD; k0 += 32) {
#pragma unroll
    for (int i = 0; i < 4; ++i) {
      int idx = t + i * 256;
      int row = idx >> 3;
      int c4  = (idx & 7) << 2;
      float4 av = *(const float4*)(X + (size_t)(m0 + row) * DD + k0 + c4);
      float4 bv4 = *(const float4*)(B + (size_t)(n0 + row) * DD + k0 + c4);
      As[c4 + 0][row] = av.x; As[c4 + 1][row] = av.y;
      As[c4 + 2][row] = av.z; As[c4 + 3][row] = av.w;
      Bs[c4 + 0][row] = bv4.x; Bs[c4 + 1][row] = bv4.y;
      Bs[c4 + 2][row] = bv4.z; Bs[c4 + 3][row] = bv4.w;
    }
    __syncthreads();
#pragma unroll
    for (int kk = 0; kk < 32; ++kk) {
      float a[8], b[8];
      *(float4*)&a[0] = *(const float4*)&As[kk][tm * 4];
      *(float4*)&a[4] = *(const float4*)&As[kk][64 + tm * 4];
      *(float4*)&b[0] = *(const float4*)&Bs[kk][tn * 4];
      *(float4*)&b[4] = *(const float4*)&Bs[kk][64 + tn * 4];
#pragma unroll
      for (int i = 0; i < 8; ++i)
#pragma unroll
        for (int j = 0; j < 8; ++j)
          acc[i][j] = fmaf(a[i], b[j], acc[i][j]);
    }
    __syncthreads();
  }

#pragma unroll
  for (int gi = 0; gi < 2; ++gi)
#pragma unroll
    for (int r = 0; r < 4; ++r) {
      const int grow = m0 + gi * 64 + tm * 4 + r;
#pragma unroll
      for (int gj = 0; gj < 2; ++gj) {
        const int gcol0 = n0 + gj * 64 + tn * 4;
        float val[4];
#pragma unroll
        for (int c = 0; c < 4; ++c)
          val[c] = acc[gi * 4 + r][gj * 4 + c] + bias[gcol0 + c];
        if (sel == 2) {
          *(float4*)(Vf + (size_t)grow * DD + gcol0) =
              make_float4(val[0], val[1], val[2], val[3]);
        } else {
          f16x4 h4, l4;
#pragma unroll
          for (int c = 0; c < 4; ++c) {
            f16 h = (f16)val[c];
            h4[c] = h;
            l4[c] = (f16)(val[c] - (float)h);
          }
          if (sel == 0) {          // Q: [hi | hi | lo]
            f16* base = Qs + (size_t)grow * 768 + gcol0;
            *(f16x4*)(base)       = h4;
            *(f16x4*)(base + 256) = h4;
            *(f16x4*)(base + 512) = l4;
          } else {                 // K: [hi | lo | hi]
            f16* base = Ks + (size_t)grow * 768 + gcol0;
            *(f16x4*)(base)       = h4;
            *(f16x4*)(base + 256) = l4;
            *(f16x4*)(base + 512) = h4;
          }
        }
      }
    }
}

// ---------------------------------------------------------------------------
// MFMA scores GEMM — R3's proven version (unchanged; 50.9us @CR=2048):
// 128x128 tile, BK=64, 4 waves, global_load_lds staging, direct C store.
// ---------------------------------------------------------------------------
typedef __attribute__((address_space(1))) const void GV;
typedef __attribute__((address_space(3))) void LV;
__device__ __forceinline__ void gl_lds16(const void* g, void* l) {
  __builtin_amdgcn_global_load_lds((GV*)g, (LV*)l, 16, 0, 0);
}

__global__ __launch_bounds__(256)
void gemm_scores_f16(const f16* __restrict__ Aq, const f16* __restrict__ Bk,
                     float* __restrict__ C, const float* __restrict__ temp,
                     int rowOff)
{
  __shared__ __align__(16) f16 As[128 * 64];
  __shared__ __align__(16) f16 Bs[128 * 64];
  const int t  = threadIdx.x;
  const int l  = t & 63;
  const int w  = t >> 6;          // wave 0..3
  const int wr = w >> 1;          // wave row quadrant
  const int wc = w & 1;           // wave col quadrant
  const int m0 = blockIdx.x * 128;
  const int n0 = blockIdx.y * 128;

  f32x4 acc[4][4];
#pragma unroll
  for (int m = 0; m < 4; ++m)
#pragma unroll
    for (int n = 0; n < 4; ++n) acc[m][n] = (f32x4){0.f, 0.f, 0.f, 0.f};

  const int lr = l >> 3;          // staging: row within 8-row segment
  const int lk = (l & 7) * 8;     // staging: k offset (f16)
  const int fr = l & 15;          // fragment row/col
  const int fg = l >> 4;          // fragment k-group (0..3)

  for (int k0 = 0; k0 < 768; k0 += 64) {
    __syncthreads();
#pragma unroll
    for (int i = 0; i < 4; ++i) {
      const int seg = w * 4 + i;  // 0..15, rows seg*8..seg*8+7
      gl_lds16(Aq + (size_t)(m0 + seg * 8 + lr) * 768 + k0 + lk, &As[seg * 512]);
      gl_lds16(Bk + (size_t)(n0 + seg * 8 + lr) * 768 + k0 + lk, &Bs[seg * 512]);
    }
    __syncthreads();
#pragma unroll
    for (int kk = 0; kk < 2; ++kk) {
      f16x8 af[4], bf[4];
#pragma unroll
      for (int m = 0; m < 4; ++m)
        af[m] = *(const f16x8*)&As[(wr * 64 + m * 16 + fr) * 64 + kk * 32 + fg * 8];
#pragma unroll
      for (int n = 0; n < 4; ++n)
        bf[n] = *(const f16x8*)&Bs[(wc * 64 + n * 16 + fr) * 64 + kk * 32 + fg * 8];
#pragma unroll
      for (int m = 0; m < 4; ++m)
#pragma unroll
        for (int n = 0; n < 4; ++n)
          acc[m][n] = __builtin_amdgcn_mfma_f32_16x16x32_f16(af[m], bf[n], acc[m][n], 0, 0, 0);
    }
  }

  const float invts = 1.0f / (temp[0] * 16.0f);
#pragma unroll
  for (int m = 0; m < 4; ++m)
#pragma unroll
    for (int n = 0; n < 4; ++n) {
      const int gcol = n0 + wc * 64 + n * 16 + fr;    // C/D: col = lane&15
#pragma unroll
      for (int j = 0; j < 4; ++j) {                   // row = (lane>>4)*4 + j
        const int lrow = m0 + wr * 64 + m * 16 + fg * 4 + j;
        float x = acc[m][n][j] * invts;
        if (rowOff + lrow == gcol) x = NEGVAL;
        C[(size_t)lrow * NN + gcol] = x;
      }
    }
}

// ---------------------------------------------------------------------------
// topk_softmax v3: same algorithm as proven v2 (exact 64th-largest, ties
// included, deterministic compaction) but all 256-wide LDS scans replaced by
// wave-level shfl scans (+4-entry combine) and the atomic candidate
// compaction replaced by a deterministic prefix -> ~12 barriers vs ~45.
// ---------------------------------------------------------------------------
__global__ __launch_bounds__(256)
void topk_softmax3(const float* __restrict__ Sc, int rowOff,
                   float* __restrict__ wts, int* __restrict__ idx,
                   int* __restrict__ cnt)
{
  __shared__ unsigned hist[256];
  __shared__ float    candv[CCAP];
  __shared__ float    pb[CAP];
  __shared__ int      jb[CAP];
  __shared__ float    wmax[4], wsum[4];
  __shared__ int      wtot[4];
  __shared__ int      sB;
  __shared__ unsigned uT;

  const int t = threadIdx.x;
  const int l = t & 63;
  const int w = t >> 6;
  const int grow = rowOff + blockIdx.x;
  const float* srow = Sc + (size_t)blockIdx.x * NN;

  float v[32];
#pragma unroll
  for (int c = 0; c < 8; ++c) {
    float4 f = *(const float4*)(srow + ((size_t)c * 256 + t) * 4);
    v[c * 4 + 0] = f.x; v[c * 4 + 1] = f.y; v[c * 4 + 2] = f.z; v[c * 4 + 3] = f.w;
  }
  // element index of v[c*4+q] = (c*256 + t)*4 + q

  // ---- block max (wave shfl + 4-entry combine) ----
  float lm = -3.0e38f;
#pragma unroll
  for (int r = 0; r < 32; ++r) lm = fmaxf(lm, v[r]);
#pragma unroll
  for (int off = 32; off; off >>= 1) lm = fmaxf(lm, __shfl_xor(lm, off));
  if (l == 0) wmax[w] = lm;
  __syncthreads();
  const float m = fmaxf(fmaxf(wmax[0], wmax[1]), fmaxf(wmax[2], wmax[3]));

  // ---- histogram over [lo, m]; widen until >= TOPK values inside ----
  float lo = m - 2.5f;
  float invw = 0.0f;
  int B = -1;
  for (int iter = 0; iter < 8; ++iter) {
    hist[t] = 0u;
    __syncthreads();
    invw = 256.0f / (m - lo);
#pragma unroll
    for (int r = 0; r < 32; ++r) {
      float s = v[r];
      if (s >= lo) {
        int b = (int)((s - lo) * invw);
        b = (b > 255) ? 255 : b;
        atomicAdd(&hist[b], 1u);
      }
    }
    __syncthreads();
    const int c = (int)hist[t];
    // wave-level inclusive suffix scan (bins t..wave_end)
    int x = c;
#pragma unroll
    for (int off = 1; off < 64; off <<= 1) {
      int y = __shfl_down(x, off);
      if (l + off < 64) x += y;
    }
    if (l == 0) wtot[w] = x;
    __syncthreads();
    int hi = 0;
#pragma unroll
    for (int ww = 0; ww < 4; ++ww) if (ww > w) hi += wtot[ww];
    const int S = x + hi;                  // count of values in bins >= t
    const int total = wtot[0] + wtot[1] + wtot[2] + wtot[3];
    if (total >= TOPK) {
      if (S >= TOPK && S - c < TOPK) sB = t;   // unique boundary bin
      __syncthreads();
      B = sB;
      break;
    }
    __syncthreads();
    lo = m - 2.5f * (float)(2 << iter);    // -5, -10, -20, ...
  }
  if (B < 0) B = 0;  // unreachable in practice

  // ---- deterministic candidate compaction (bin >= B) ----
  int cc = 0;
#pragma unroll
  for (int r = 0; r < 32; ++r) {
    float s = v[r];
    if (s >= lo) {
      int b = (int)((s - lo) * invw);
      b = (b > 255) ? 255 : b;
      if (b >= B) ++cc;
    }
  }
  {
    int x = cc;
#pragma unroll
    for (int off = 1; off < 64; off <<= 1) {
      int y = __shfl_up(x, off);
      if (l >= off) x += y;
    }
    if (l == 63) wtot[w] = x;
    __syncthreads();
    int lowsum = 0;
#pragma unroll
    for (int ww = 0; ww < 4; ++ww) if (ww < w) lowsum += wtot[ww];
    int base = lowsum + x - cc;            // exclusive prefix
    const int ctotal = wtot[0] + wtot[1] + wtot[2] + wtot[3];
#pragma unroll
    for (int r = 0; r < 32; ++r) {
      float s = v[r];
      if (s >= lo) {
        int b = (int)((s - lo) * invw);
        b = (b > 255) ? 255 : b;
        if (b >= B) {
          if (base < CCAP) candv[base] = s;
          ++base;
        }
      }
    }
    __syncthreads();
    const int L = (ctotal < CCAP) ? ctotal : CCAP;

    // ---- exact 64th-largest among candidates ----
    if (t == 0) uT = 0xFFFFFFFFu;
    __syncthreads();
    for (int i = t; i < L; i += 256) {
      float vi = candv[i];
      int g = 0;
      for (int j = 0; j < L; ++j) g += (candv[j] > vi) ? 1 : 0;
      if (g <= TOPK - 1) {
        unsigned ub = __float_as_uint(vi);
        unsigned u = (ub & 0x80000000u) ? ~ub : (ub | 0x80000000u);
        atomicMin(&uT, u);
      }
    }
    __syncthreads();
  }
  const unsigned uth = uT;
  const float T = __uint_as_float((uth & 0x80000000u) ? (uth & 0x7FFFFFFFu) : ~uth);

  // ---- deterministic survivor compaction (s >= T, ties included) ----
  int myc = 0;
#pragma unroll
  for (int r = 0; r < 32; ++r) myc += (v[r] >= T) ? 1 : 0;
  int x2 = myc;
#pragma unroll
  for (int off = 1; off < 64; off <<= 1) {
    int y = __shfl_up(x2, off);
    if (l >= off) x2 += y;
  }
  if (l == 63) wtot[w] = x2;
  __syncthreads();
  int lowsum2 = 0;
#pragma unroll
  for (int ww = 0; ww < 4; ++ww) if (ww < w) lowsum2 += wtot[ww];
  int base = lowsum2 + x2 - myc;
  const int total2 = wtot[0] + wtot[1] + wtot[2] + wtot[3];
#pragma unroll
  for (int r = 0; r < 32; ++r) {
    if (v[r] >= T) {
      if (base < CAP) {
        pb[base] = __expf(v[r] - m);
        jb[base] = ((r >> 2) * 256 + t) * 4 + (r & 3);
      }
      ++base;
    }
  }
  __syncthreads();
  const int L2 = (total2 < CAP) ? total2 : CAP;

  // ---- deterministic psum + write normalized weights ----
  float ps = 0.0f;
  for (int i = t; i < L2; i += 256) ps += pb[i];
#pragma unroll
  for (int off = 32; off; off >>= 1) ps += __shfl_xor(ps, off);
  if (l == 0) wsum[w] = ps;
  __syncthreads();
  const float inv = 1.0f / (wsum[0] + wsum[1] + wsum[2] + wsum[3]);
  for (int i = t; i < L2; i += 256) {
    wts[(size_t)grow * CAP + i] = pb[i] * inv;
    idx[(size_t)grow * CAP + i] = jb[i];
  }
  if (t == 0) cnt[grow] = L2;
}

// ---------------------------------------------------------------------------
__global__ __launch_bounds__(256)
void sparse_av(const float* __restrict__ V, const float* __restrict__ wts,
               const int* __restrict__ idx, const int* __restrict__ cnt,
               float* __restrict__ out)
{
  __shared__ float wl[CAP];
  __shared__ int   jl[CAP];
  const int t = threadIdx.x;
  const int row = blockIdx.x;
  const int L = cnt[row];
  if (t < CAP && t < L) {
    wl[t] = wts[(size_t)row * CAP + t];
    jl[t] = idx[(size_t)row * CAP + t];
  }
  __syncthreads();
  float acc = 0.0f;
  for (int i = 0; i < L; ++i)
    acc = fmaf(wl[i], V[(size_t)jl[i] * DD + t], acc);
  out[(size_t)row * DD + t] = acc;
}

// ---------------------------------------------------------------------------
extern "C" void kernel_launch(void* const* d_in, const int* in_sizes, int n_in,
                              void* d_out, int out_size, void* d_ws, size_t ws_size,
                              hipStream_t stream)
{
  const float* X    = (const float*)d_in[0];
  const float* Wq   = (const float*)d_in[1];
  const float* bq   = (const float*)d_in[2];
  const float* Wk   = (const float*)d_in[3];
  const float* bk   = (const float*)d_in[4];
  const float* Wv   = (const float*)d_in[5];
  const float* bv   = (const float*)d_in[6];
  const float* temp = (const float*)d_in[7];
  float* out = (float*)d_out;
  float* ws  = (float*)d_ws;

  const size_t avail = ws_size / sizeof(float);

  const size_t szV   = (size_t)NN * DD;          // V f32
  const size_t szHL  = (size_t)NN * 768 / 2;     // f16 hi/lo buf (float units)
  const size_t szWts = (size_t)NN * CAP;
  const size_t szIdx = (size_t)NN * CAP;
  const size_t szCnt = NN;
  const size_t fixed = szV + 2 * szHL + szWts + szIdx + szCnt;

  size_t o = 0;
  float* Vbuf = ws + o; o += szV;
  f16*   Qs   = (f16*)(ws + o); o += szHL;
  f16*   Ks   = (f16*)(ws + o); o += szHL;
  float* wts  = ws + o; o += szWts;
  int*   idxb = (int*)(ws + o); o += szIdx;
  int*   cntb = (int*)(ws + o); o += szCnt;

  if (avail <= fixed + (size_t)128 * NN) return;
  int CR = (int)(((avail - fixed) / NN) / 128) * 128;
  if (CR > CRMAX) CR = CRMAX;       // 64 MB chunk: write->read->overwrite
  if (CR > NN) CR = NN;             // cycle stays L3-resident
  float* Sc = ws + o;

  dim3 blk(256);

  // fused Q/K/V projections with direct f16 hi/lo epilogue
  gemm_qkv<<<dim3(NN/128, 6), blk, 0, stream>>>(X, Wq, bq, Wk, bk, Wv, bv,
                                                Qs, Ks, Vbuf);

  for (int r0 = 0; r0 < NN; r0 += CR) {
    const int rows = (NN - r0 < CR) ? (NN - r0) : CR;
    gemm_scores_f16<<<dim3(rows/128, NN/128), blk, 0, stream>>>(
        Qs + (size_t)r0 * 768, Ks, Sc, temp, r0);
    topk_softmax3<<<dim3(rows), blk, 0, stream>>>(Sc, r0, wts, idxb, cntb);
  }

  sparse_av<<<dim3(NN), blk, 0, stream>>>(Vbuf, wts, idxb, cntb, out);
}

// Round 10
// 387.414 us; speedup vs baseline: 1.4118x; 1.0093x over previous
//
#include <hip/hip_runtime.h>
#include <math.h>

#define NN 8192
#define DD 256
#define TOPK 64
#define CAP 96            // survivor capacity per row
#define CCAP 256          // candidate capacity for exact select
#define CRMAX 2048        // score-chunk rows: Sc = 64 MB -> L3-resident
#define NEGVAL (-1000000000.0f)

typedef _Float16 f16;
typedef f16  f16x4 __attribute__((ext_vector_type(4)));
typedef f16  f16x8 __attribute__((ext_vector_type(8)));
typedef float f32x4 __attribute__((ext_vector_type(4)));

// ---------------------------------------------------------------------------
// Fused QKV projection, 64x64 tiles for occupancy (1536 blocks vs R8's 384).
//   grid (NN/64, 12): sel = y>>2 (0=Q,1=K,2=V), n0 = (y&3)*64.
// Per-output fmaf chain is k-ascending (identical order to the R8 kernel) ->
// bitwise-identical Q/K/V. Q,K written directly as f16 hi/lo score layout:
//   Qs[row] = [Qhi | Qhi | Qlo],  Ks[row] = [Khi | Klo | Khi];  V as f32.
// ---------------------------------------------------------------------------
__global__ __launch_bounds__(256)
void gemm_qkv(const float* __restrict__ X,
              const float* __restrict__ Wq, const float* __restrict__ bq,
              const float* __restrict__ Wk, const float* __restrict__ bk,
              const float* __restrict__ Wv, const float* __restrict__ bv,
              f16* __restrict__ Qs, f16* __restrict__ Ks,
              float* __restrict__ Vf)
{
  __shared__ float As[32][64];
  __shared__ float Bs[32][64];
  const int t  = threadIdx.x;
  const int tm = t & 15;
  const int tn = t >> 4;
  const int m0 = blockIdx.x * 64;
  const int sel = blockIdx.y >> 2;
  const int n0  = (blockIdx.y & 3) * 64;
  const float* B    = (sel == 0) ? Wq : (sel == 1) ? Wk : Wv;
  const float* bias = (sel == 0) ? bq : (sel == 1) ? bk : bv;

  float acc[4][4];
#pragma unroll
  for (int i = 0; i < 4; ++i)
#pragma unroll
    for (int j = 0; j < 4; ++j) acc[i][j] = 0.0f;

  for (int k0 = 0; k0 < DD; k0 += 32) {
#pragma unroll
    for (int i = 0; i < 2; ++i) {
      int slot = t + i * 256;         // 0..511 float4 slots
      int row  = slot >> 3;           // 0..63
      int c4   = (slot & 7) << 2;     // 0,4,..,28
      float4 av  = *(const float4*)(X + (size_t)(m0 + row) * DD + k0 + c4);
      float4 bv4 = *(const float4*)(B + (size_t)(n0 + row) * DD + k0 + c4);
      As[c4 + 0][row] = av.x;  As[c4 + 1][row] = av.y;
      As[c4 + 2][row] = av.z;  As[c4 + 3][row] = av.w;
      Bs[c4 + 0][row] = bv4.x; Bs[c4 + 1][row] = bv4.y;
      Bs[c4 + 2][row] = bv4.z; Bs[c4 + 3][row] = bv4.w;
    }
    __syncthreads();
#pragma unroll
    for (int kk = 0; kk < 32; ++kk) {
      float a[4], b[4];
      *(float4*)&a[0] = *(const float4*)&As[kk][tm * 4];
      *(float4*)&b[0] = *(const float4*)&Bs[kk][tn * 4];
#pragma unroll
      for (int i = 0; i < 4; ++i)
#pragma unroll
        for (int j = 0; j < 4; ++j)
          acc[i][j] = fmaf(a[i], b[j], acc[i][j]);
    }
    __syncthreads();
  }

#pragma unroll
  for (int r = 0; r < 4; ++r) {
    const int grow  = m0 + tm * 4 + r;
    const int gcol0 = n0 + tn * 4;
    float val[4];
#pragma unroll
    for (int c = 0; c < 4; ++c)
      val[c] = acc[r][c] + bias[gcol0 + c];
    if (sel == 2) {
      *(float4*)(Vf + (size_t)grow * DD + gcol0) =
          make_float4(val[0], val[1], val[2], val[3]);
    } else {
      f16x4 h4, l4;
#pragma unroll
      for (int c = 0; c < 4; ++c) {
        f16 h = (f16)val[c];
        h4[c] = h;
        l4[c] = (f16)(val[c] - (float)h);
      }
      if (sel == 0) {            // Q: [hi | hi | lo]
        f16* base = Qs + (size_t)grow * 768 + gcol0;
        *(f16x4*)(base)       = h4;
        *(f16x4*)(base + 256) = h4;
        *(f16x4*)(base + 512) = l4;
      } else {                   // K: [hi | lo | hi]
        f16* base = Ks + (size_t)grow * 768 + gcol0;
        *(f16x4*)(base)       = h4;
        *(f16x4*)(base + 256) = l4;
        *(f16x4*)(base + 512) = h4;
      }
    }
  }
}

// ---------------------------------------------------------------------------
// MFMA scores GEMM — R3's proven version (unchanged; 50.9us @CR=2048):
// 128x128 tile, BK=64, 4 waves, global_load_lds staging, direct C store.
// ---------------------------------------------------------------------------
typedef __attribute__((address_space(1))) const void GV;
typedef __attribute__((address_space(3))) void LV;
__device__ __forceinline__ void gl_lds16(const void* g, void* l) {
  __builtin_amdgcn_global_load_lds((GV*)g, (LV*)l, 16, 0, 0);
}

__global__ __launch_bounds__(256)
void gemm_scores_f16(const f16* __restrict__ Aq, const f16* __restrict__ Bk,
                     float* __restrict__ C, const float* __restrict__ temp,
                     int rowOff)
{
  __shared__ __align__(16) f16 As[128 * 64];
  __shared__ __align__(16) f16 Bs[128 * 64];
  const int t  = threadIdx.x;
  const int l  = t & 63;
  const int w  = t >> 6;          // wave 0..3
  const int wr = w >> 1;          // wave row quadrant
  const int wc = w & 1;           // wave col quadrant
  const int m0 = blockIdx.x * 128;
  const int n0 = blockIdx.y * 128;

  f32x4 acc[4][4];
#pragma unroll
  for (int m = 0; m < 4; ++m)
#pragma unroll
    for (int n = 0; n < 4; ++n) acc[m][n] = (f32x4){0.f, 0.f, 0.f, 0.f};

  const int lr = l >> 3;          // staging: row within 8-row segment
  const int lk = (l & 7) * 8;     // staging: k offset (f16)
  const int fr = l & 15;          // fragment row/col
  const int fg = l >> 4;          // fragment k-group (0..3)

  for (int k0 = 0; k0 < 768; k0 += 64) {
    __syncthreads();
#pragma unroll
    for (int i = 0; i < 4; ++i) {
      const int seg = w * 4 + i;  // 0..15, rows seg*8..seg*8+7
      gl_lds16(Aq + (size_t)(m0 + seg * 8 + lr) * 768 + k0 + lk, &As[seg * 512]);
      gl_lds16(Bk + (size_t)(n0 + seg * 8 + lr) * 768 + k0 + lk, &Bs[seg * 512]);
    }
    __syncthreads();
#pragma unroll
    for (int kk = 0; kk < 2; ++kk) {
      f16x8 af[4], bf[4];
#pragma unroll
      for (int m = 0; m < 4; ++m)
        af[m] = *(const f16x8*)&As[(wr * 64 + m * 16 + fr) * 64 + kk * 32 + fg * 8];
#pragma unroll
      for (int n = 0; n < 4; ++n)
        bf[n] = *(const f16x8*)&Bs[(wc * 64 + n * 16 + fr) * 64 + kk * 32 + fg * 8];
#pragma unroll
      for (int m = 0; m < 4; ++m)
#pragma unroll
        for (int n = 0; n < 4; ++n)
          acc[m][n] = __builtin_amdgcn_mfma_f32_16x16x32_f16(af[m], bf[n], acc[m][n], 0, 0, 0);
    }
  }

  const float invts = 1.0f / (temp[0] * 16.0f);
#pragma unroll
  for (int m = 0; m < 4; ++m)
#pragma unroll
    for (int n = 0; n < 4; ++n) {
      const int gcol = n0 + wc * 64 + n * 16 + fr;    // C/D: col = lane&15
#pragma unroll
      for (int j = 0; j < 4; ++j) {                   // row = (lane>>4)*4 + j
        const int lrow = m0 + wr * 64 + m * 16 + fg * 4 + j;
        float x = acc[m][n][j] * invts;
        if (rowOff + lrow == gcol) x = NEGVAL;
        C[(size_t)lrow * NN + gcol] = x;
      }
    }
}

// ---------------------------------------------------------------------------
// topk_softmax v3 (proven R8): wave-level scans, exact 64th-largest,
// deterministic compaction.
// ---------------------------------------------------------------------------
__global__ __launch_bounds__(256)
void topk_softmax3(const float* __restrict__ Sc, int rowOff,
                   float* __restrict__ wts, int* __restrict__ idx,
                   int* __restrict__ cnt)
{
  __shared__ unsigned hist[256];
  __shared__ float    candv[CCAP];
  __shared__ float    pb[CAP];
  __shared__ int      jb[CAP];
  __shared__ float    wmax[4], wsum[4];
  __shared__ int      wtot[4];
  __shared__ int      sB;
  __shared__ unsigned uT;

  const int t = threadIdx.x;
  const int l = t & 63;
  const int w = t >> 6;
  const int grow = rowOff + blockIdx.x;
  const float* srow = Sc + (size_t)blockIdx.x * NN;

  float v[32];
#pragma unroll
  for (int c = 0; c < 8; ++c) {
    float4 f = *(const float4*)(srow + ((size_t)c * 256 + t) * 4);
    v[c * 4 + 0] = f.x; v[c * 4 + 1] = f.y; v[c * 4 + 2] = f.z; v[c * 4 + 3] = f.w;
  }

  float lm = -3.0e38f;
#pragma unroll
  for (int r = 0; r < 32; ++r) lm = fmaxf(lm, v[r]);
#pragma unroll
  for (int off = 32; off; off >>= 1) lm = fmaxf(lm, __shfl_xor(lm, off));
  if (l == 0) wmax[w] = lm;
  __syncthreads();
  const float m = fmaxf(fmaxf(wmax[0], wmax[1]), fmaxf(wmax[2], wmax[3]));

  float lo = m - 2.5f;
  float invw = 0.0f;
  int B = -1;
  for (int iter = 0; iter < 8; ++iter) {
    hist[t] = 0u;
    __syncthreads();
    invw = 256.0f / (m - lo);
#pragma unroll
    for (int r = 0; r < 32; ++r) {
      float s = v[r];
      if (s >= lo) {
        int b = (int)((s - lo) * invw);
        b = (b > 255) ? 255 : b;
        atomicAdd(&hist[b], 1u);
      }
    }
    __syncthreads();
    const int c = (int)hist[t];
    int x = c;
#pragma unroll
    for (int off = 1; off < 64; off <<= 1) {
      int y = __shfl_down(x, off);
      if (l + off < 64) x += y;
    }
    if (l == 0) wtot[w] = x;
    __syncthreads();
    int hi = 0;
#pragma unroll
    for (int ww = 0; ww < 4; ++ww) if (ww > w) hi += wtot[ww];
    const int S = x + hi;
    const int total = wtot[0] + wtot[1] + wtot[2] + wtot[3];
    if (total >= TOPK) {
      if (S >= TOPK && S - c < TOPK) sB = t;
      __syncthreads();
      B = sB;
      break;
    }
    __syncthreads();
    lo = m - 2.5f * (float)(2 << iter);
  }
  if (B < 0) B = 0;

  int cc = 0;
#pragma unroll
  for (int r = 0; r < 32; ++r) {
    float s = v[r];
    if (s >= lo) {
      int b = (int)((s - lo) * invw);
      b = (b > 255) ? 255 : b;
      if (b >= B) ++cc;
    }
  }
  {
    int x = cc;
#pragma unroll
    for (int off = 1; off < 64; off <<= 1) {
      int y = __shfl_up(x, off);
      if (l >= off) x += y;
    }
    if (l == 63) wtot[w] = x;
    __syncthreads();
    int lowsum = 0;
#pragma unroll
    for (int ww = 0; ww < 4; ++ww) if (ww < w) lowsum += wtot[ww];
    int base = lowsum + x - cc;
    const int ctotal = wtot[0] + wtot[1] + wtot[2] + wtot[3];
#pragma unroll
    for (int r = 0; r < 32; ++r) {
      float s = v[r];
      if (s >= lo) {
        int b = (int)((s - lo) * invw);
        b = (b > 255) ? 255 : b;
        if (b >= B) {
          if (base < CCAP) candv[base] = s;
          ++base;
        }
      }
    }
    __syncthreads();
    const int L = (ctotal < CCAP) ? ctotal : CCAP;

    if (t == 0) uT = 0xFFFFFFFFu;
    __syncthreads();
    for (int i = t; i < L; i += 256) {
      float vi = candv[i];
      int g = 0;
      for (int j = 0; j < L; ++j) g += (candv[j] > vi) ? 1 : 0;
      if (g <= TOPK - 1) {
        unsigned ub = __float_as_uint(vi);
        unsigned u = (ub & 0x80000000u) ? ~ub : (ub | 0x80000000u);
        atomicMin(&uT, u);
      }
    }
    __syncthreads();
  }
  const unsigned uth = uT;
  const float T = __uint_as_float((uth & 0x80000000u) ? (uth & 0x7FFFFFFFu) : ~uth);

  int myc = 0;
#pragma unroll
  for (int r = 0; r < 32; ++r) myc += (v[r] >= T) ? 1 : 0;
  int x2 = myc;
#pragma unroll
  for (int off = 1; off < 64; off <<= 1) {
    int y = __shfl_up(x2, off);
    if (l >= off) x2 += y;
  }
  if (l == 63) wtot[w] = x2;
  __syncthreads();
  int lowsum2 = 0;
#pragma unroll
  for (int ww = 0; ww < 4; ++ww) if (ww < w) lowsum2 += wtot[ww];
  int base = lowsum2 + x2 - myc;
  const int total2 = wtot[0] + wtot[1] + wtot[2] + wtot[3];
#pragma unroll
  for (int r = 0; r < 32; ++r) {
    if (v[r] >= T) {
      if (base < CAP) {
        pb[base] = __expf(v[r] - m);
        jb[base] = ((r >> 2) * 256 + t) * 4 + (r & 3);
      }
      ++base;
    }
  }
  __syncthreads();
  const int L2 = (total2 < CAP) ? total2 : CAP;

  float ps = 0.0f;
  for (int i = t; i < L2; i += 256) ps += pb[i];
#pragma unroll
  for (int off = 32; off; off >>= 1) ps += __shfl_xor(ps, off);
  if (l == 0) wsum[w] = ps;
  __syncthreads();
  const float inv = 1.0f / (wsum[0] + wsum[1] + wsum[2] + wsum[3]);
  for (int i = t; i < L2; i += 256) {
    wts[(size_t)grow * CAP + i] = pb[i] * inv;
    idx[(size_t)grow * CAP + i] = jb[i];
  }
  if (t == 0) cnt[grow] = L2;
}

// ---------------------------------------------------------------------------
__global__ __launch_bounds__(256)
void sparse_av(const float* __restrict__ V, const float* __restrict__ wts,
               const int* __restrict__ idx, const int* __restrict__ cnt,
               float* __restrict__ out)
{
  __shared__ float wl[CAP];
  __shared__ int   jl[CAP];
  const int t = threadIdx.x;
  const int row = blockIdx.x;
  const int L = cnt[row];
  if (t < CAP && t < L) {
    wl[t] = wts[(size_t)row * CAP + t];
    jl[t] = idx[(size_t)row * CAP + t];
  }
  __syncthreads();
  float acc = 0.0f;
  for (int i = 0; i < L; ++i)
    acc = fmaf(wl[i], V[(size_t)jl[i] * DD + t], acc);
  out[(size_t)row * DD + t] = acc;
}

// ---------------------------------------------------------------------------
extern "C" void kernel_launch(void* const* d_in, const int* in_sizes, int n_in,
                              void* d_out, int out_size, void* d_ws, size_t ws_size,
                              hipStream_t stream)
{
  const float* X    = (const float*)d_in[0];
  const float* Wq   = (const float*)d_in[1];
  const float* bq   = (const float*)d_in[2];
  const float* Wk   = (const float*)d_in[3];
  const float* bk   = (const float*)d_in[4];
  const float* Wv   = (const float*)d_in[5];
  const float* bv   = (const float*)d_in[6];
  const float* temp = (const float*)d_in[7];
  float* out = (float*)d_out;
  float* ws  = (float*)d_ws;

  const size_t avail = ws_size / sizeof(float);

  const size_t szV   = (size_t)NN * DD;          // V f32
  const size_t szHL  = (size_t)NN * 768 / 2;     // f16 hi/lo buf (float units)
  const size_t szWts = (size_t)NN * CAP;
  const size_t szIdx = (size_t)NN * CAP;
  const size_t szCnt = NN;
  const size_t fixed = szV + 2 * szHL + szWts + szIdx + szCnt;

  size_t o = 0;
  float* Vbuf = ws + o; o += szV;
  f16*   Qs   = (f16*)(ws + o); o += szHL;
  f16*   Ks   = (f16*)(ws + o); o += szHL;
  float* wts  = ws + o; o += szWts;
  int*   idxb = (int*)(ws + o); o += szIdx;
  int*   cntb = (int*)(ws + o); o += szCnt;

  if (avail <= fixed + (size_t)128 * NN) return;
  int CR = (int)(((avail - fixed) / NN) / 128) * 128;
  if (CR > CRMAX) CR = CRMAX;       // 64 MB chunk: write->read->overwrite
  if (CR > NN) CR = NN;             // cycle stays L3-resident
  float* Sc = ws + o;

  dim3 blk(256);

  // fused Q/K/V projections (exact f32 math; 64x64 tiles for occupancy)
  gemm_qkv<<<dim3(NN/64, 12), blk, 0, stream>>>(X, Wq, bq, Wk, bk, Wv, bv,
                                                Qs, Ks, Vbuf);

  for (int r0 = 0; r0 < NN; r0 += CR) {
    const int rows = (NN - r0 < CR) ? (NN - r0) : CR;
    gemm_scores_f16<<<dim3(rows/128, NN/128), blk, 0, stream>>>(
        Qs + (size_t)r0 * 768, Ks, Sc, temp, r0);
    topk_softmax3<<<dim3(rows), blk, 0, stream>>>(Sc, r0, wts, idxb, cntb);
  }

  sparse_av<<<dim3(NN), blk, 0, stream>>>(Vbuf, wts, idxb, cntb, out);
}

// Round 11
// 378.730 us; speedup vs baseline: 1.4442x; 1.0229x over previous
//
#include <hip/hip_runtime.h>
#include <math.h>

#define NN 8192
#define DD 256
#define TOPK 64
#define CAP 96            // survivor capacity per row
#define CCAP 256          // candidate capacity for exact select
#define CRMAX 2048        // score-chunk rows: Sc = 64 MB -> L3-resident
#define NEGVAL (-1000000000.0f)

typedef _Float16 f16;
typedef f16  f16x4 __attribute__((ext_vector_type(4)));
typedef f16  f16x8 __attribute__((ext_vector_type(8)));
typedef float f32x4 __attribute__((ext_vector_type(4)));

// ---------------------------------------------------------------------------
// Fused QKV projection v3: ONE block computes the Q, K and V 64x64 tiles for
// its (m0,n0), sharing the staged X tile across all three weight matrices
// (LDS compute-reads: 64 B per 48 fmaf vs 32 B per 16 before). LDS rows
// padded to stride 68 (272 B, b128-aligned) -> staging-write bank conflicts
// drop 8-way -> 4-way. Per-output fmaf chain is k-ascending, identical order
// to R10 -> bitwise-identical Q/K/V (selection boundary demands exactness).
// Q,K written directly as f16 hi/lo score layout; V as f32.
// ---------------------------------------------------------------------------
__global__ __launch_bounds__(256)
void gemm_qkv(const float* __restrict__ X,
              const float* __restrict__ Wq, const float* __restrict__ bq,
              const float* __restrict__ Wk, const float* __restrict__ bk,
              const float* __restrict__ Wv, const float* __restrict__ bv,
              f16* __restrict__ Qs, f16* __restrict__ Ks,
              float* __restrict__ Vf)
{
  __shared__ float As[32][68];        // k-major, +4 pad: 16B-aligned rows
  __shared__ float Bs[3][32][68];
  const int t  = threadIdx.x;
  const int tm = t & 15;
  const int tn = t >> 4;
  const int m0 = blockIdx.x * 64;
  const int n0 = blockIdx.y * 64;

  float acc[3][4][4];
#pragma unroll
  for (int g = 0; g < 3; ++g)
#pragma unroll
    for (int i = 0; i < 4; ++i)
#pragma unroll
      for (int j = 0; j < 4; ++j) acc[g][i][j] = 0.0f;

  for (int k0 = 0; k0 < DD; k0 += 32) {
    __syncthreads();
#pragma unroll
    for (int i = 0; i < 2; ++i) {
      const int slot = t + i * 256;       // 0..511
      const int row  = slot >> 3;         // 0..63
      const int c4   = (slot & 7) << 2;   // 0,4,..,28
      float4 av = *(const float4*)(X + (size_t)(m0 + row) * DD + k0 + c4);
      As[c4 + 0][row] = av.x; As[c4 + 1][row] = av.y;
      As[c4 + 2][row] = av.z; As[c4 + 3][row] = av.w;
      float4 q4 = *(const float4*)(Wq + (size_t)(n0 + row) * DD + k0 + c4);
      Bs[0][c4 + 0][row] = q4.x; Bs[0][c4 + 1][row] = q4.y;
      Bs[0][c4 + 2][row] = q4.z; Bs[0][c4 + 3][row] = q4.w;
      float4 k4 = *(const float4*)(Wk + (size_t)(n0 + row) * DD + k0 + c4);
      Bs[1][c4 + 0][row] = k4.x; Bs[1][c4 + 1][row] = k4.y;
      Bs[1][c4 + 2][row] = k4.z; Bs[1][c4 + 3][row] = k4.w;
      float4 v4 = *(const float4*)(Wv + (size_t)(n0 + row) * DD + k0 + c4);
      Bs[2][c4 + 0][row] = v4.x; Bs[2][c4 + 1][row] = v4.y;
      Bs[2][c4 + 2][row] = v4.z; Bs[2][c4 + 3][row] = v4.w;
    }
    __syncthreads();
#pragma unroll
    for (int kk = 0; kk < 32; ++kk) {
      float a[4];
      *(float4*)&a[0] = *(const float4*)&As[kk][tm * 4];
      float b0[4], b1[4], b2[4];
      *(float4*)&b0[0] = *(const float4*)&Bs[0][kk][tn * 4];
      *(float4*)&b1[0] = *(const float4*)&Bs[1][kk][tn * 4];
      *(float4*)&b2[0] = *(const float4*)&Bs[2][kk][tn * 4];
#pragma unroll
      for (int i = 0; i < 4; ++i)
#pragma unroll
        for (int j = 0; j < 4; ++j) {
          acc[0][i][j] = fmaf(a[i], b0[j], acc[0][i][j]);
          acc[1][i][j] = fmaf(a[i], b1[j], acc[1][i][j]);
          acc[2][i][j] = fmaf(a[i], b2[j], acc[2][i][j]);
        }
    }
  }

#pragma unroll
  for (int r = 0; r < 4; ++r) {
    const int grow  = m0 + tm * 4 + r;
    const int gcol0 = n0 + tn * 4;
    // Q -> f16 hi/lo [hi|hi|lo]
    {
      f16x4 h4, l4;
#pragma unroll
      for (int c = 0; c < 4; ++c) {
        const float val = acc[0][r][c] + bq[gcol0 + c];
        f16 h = (f16)val;
        h4[c] = h;
        l4[c] = (f16)(val - (float)h);
      }
      f16* base = Qs + (size_t)grow * 768 + gcol0;
      *(f16x4*)(base)       = h4;
      *(f16x4*)(base + 256) = h4;
      *(f16x4*)(base + 512) = l4;
    }
    // K -> f16 hi/lo [hi|lo|hi]
    {
      f16x4 h4, l4;
#pragma unroll
      for (int c = 0; c < 4; ++c) {
        const float val = acc[1][r][c] + bk[gcol0 + c];
        f16 h = (f16)val;
        h4[c] = h;
        l4[c] = (f16)(val - (float)h);
      }
      f16* base = Ks + (size_t)grow * 768 + gcol0;
      *(f16x4*)(base)       = h4;
      *(f16x4*)(base + 256) = l4;
      *(f16x4*)(base + 512) = h4;
    }
    // V -> f32
    {
      float val[4];
#pragma unroll
      for (int c = 0; c < 4; ++c)
        val[c] = acc[2][r][c] + bv[gcol0 + c];
      *(float4*)(Vf + (size_t)grow * DD + gcol0) =
          make_float4(val[0], val[1], val[2], val[3]);
    }
  }
}

// ---------------------------------------------------------------------------
// MFMA scores GEMM — R3's proven version (unchanged; 50.9us @CR=2048):
// 128x128 tile, BK=64, 4 waves, global_load_lds staging, direct C store.
// ---------------------------------------------------------------------------
typedef __attribute__((address_space(1))) const void GV;
typedef __attribute__((address_space(3))) void LV;
__device__ __forceinline__ void gl_lds16(const void* g, void* l) {
  __builtin_amdgcn_global_load_lds((GV*)g, (LV*)l, 16, 0, 0);
}

__global__ __launch_bounds__(256)
void gemm_scores_f16(const f16* __restrict__ Aq, const f16* __restrict__ Bk,
                     float* __restrict__ C, const float* __restrict__ temp,
                     int rowOff)
{
  __shared__ __align__(16) f16 As[128 * 64];
  __shared__ __align__(16) f16 Bs[128 * 64];
  const int t  = threadIdx.x;
  const int l  = t & 63;
  const int w  = t >> 6;          // wave 0..3
  const int wr = w >> 1;          // wave row quadrant
  const int wc = w & 1;           // wave col quadrant
  const int m0 = blockIdx.x * 128;
  const int n0 = blockIdx.y * 128;

  f32x4 acc[4][4];
#pragma unroll
  for (int m = 0; m < 4; ++m)
#pragma unroll
    for (int n = 0; n < 4; ++n) acc[m][n] = (f32x4){0.f, 0.f, 0.f, 0.f};

  const int lr = l >> 3;          // staging: row within 8-row segment
  const int lk = (l & 7) * 8;     // staging: k offset (f16)
  const int fr = l & 15;          // fragment row/col
  const int fg = l >> 4;          // fragment k-group (0..3)

  for (int k0 = 0; k0 < 768; k0 += 64) {
    __syncthreads();
#pragma unroll
    for (int i = 0; i < 4; ++i) {
      const int seg = w * 4 + i;  // 0..15, rows seg*8..seg*8+7
      gl_lds16(Aq + (size_t)(m0 + seg * 8 + lr) * 768 + k0 + lk, &As[seg * 512]);
      gl_lds16(Bk + (size_t)(n0 + seg * 8 + lr) * 768 + k0 + lk, &Bs[seg * 512]);
    }
    __syncthreads();
#pragma unroll
    for (int kk = 0; kk < 2; ++kk) {
      f16x8 af[4], bf[4];
#pragma unroll
      for (int m = 0; m < 4; ++m)
        af[m] = *(const f16x8*)&As[(wr * 64 + m * 16 + fr) * 64 + kk * 32 + fg * 8];
#pragma unroll
      for (int n = 0; n < 4; ++n)
        bf[n] = *(const f16x8*)&Bs[(wc * 64 + n * 16 + fr) * 64 + kk * 32 + fg * 8];
#pragma unroll
      for (int m = 0; m < 4; ++m)
#pragma unroll
        for (int n = 0; n < 4; ++n)
          acc[m][n] = __builtin_amdgcn_mfma_f32_16x16x32_f16(af[m], bf[n], acc[m][n], 0, 0, 0);
    }
  }

  const float invts = 1.0f / (temp[0] * 16.0f);
#pragma unroll
  for (int m = 0; m < 4; ++m)
#pragma unroll
    for (int n = 0; n < 4; ++n) {
      const int gcol = n0 + wc * 64 + n * 16 + fr;    // C/D: col = lane&15
#pragma unroll
      for (int j = 0; j < 4; ++j) {                   // row = (lane>>4)*4 + j
        const int lrow = m0 + wr * 64 + m * 16 + fg * 4 + j;
        float x = acc[m][n][j] * invts;
        if (rowOff + lrow == gcol) x = NEGVAL;
        C[(size_t)lrow * NN + gcol] = x;
      }
    }
}

// ---------------------------------------------------------------------------
// topk_softmax v3 (proven R8): wave-level scans, exact 64th-largest,
// deterministic compaction.
// ---------------------------------------------------------------------------
__global__ __launch_bounds__(256)
void topk_softmax3(const float* __restrict__ Sc, int rowOff,
                   float* __restrict__ wts, int* __restrict__ idx,
                   int* __restrict__ cnt)
{
  __shared__ unsigned hist[256];
  __shared__ float    candv[CCAP];
  __shared__ float    pb[CAP];
  __shared__ int      jb[CAP];
  __shared__ float    wmax[4], wsum[4];
  __shared__ int      wtot[4];
  __shared__ int      sB;
  __shared__ unsigned uT;

  const int t = threadIdx.x;
  const int l = t & 63;
  const int w = t >> 6;
  const int grow = rowOff + blockIdx.x;
  const float* srow = Sc + (size_t)blockIdx.x * NN;

  float v[32];
#pragma unroll
  for (int c = 0; c < 8; ++c) {
    float4 f = *(const float4*)(srow + ((size_t)c * 256 + t) * 4);
    v[c * 4 + 0] = f.x; v[c * 4 + 1] = f.y; v[c * 4 + 2] = f.z; v[c * 4 + 3] = f.w;
  }

  float lm = -3.0e38f;
#pragma unroll
  for (int r = 0; r < 32; ++r) lm = fmaxf(lm, v[r]);
#pragma unroll
  for (int off = 32; off; off >>= 1) lm = fmaxf(lm, __shfl_xor(lm, off));
  if (l == 0) wmax[w] = lm;
  __syncthreads();
  const float m = fmaxf(fmaxf(wmax[0], wmax[1]), fmaxf(wmax[2], wmax[3]));

  float lo = m - 2.5f;
  float invw = 0.0f;
  int B = -1;
  for (int iter = 0; iter < 8; ++iter) {
    hist[t] = 0u;
    __syncthreads();
    invw = 256.0f / (m - lo);
#pragma unroll
    for (int r = 0; r < 32; ++r) {
      float s = v[r];
      if (s >= lo) {
        int b = (int)((s - lo) * invw);
        b = (b > 255) ? 255 : b;
        atomicAdd(&hist[b], 1u);
      }
    }
    __syncthreads();
    const int c = (int)hist[t];
    int x = c;
#pragma unroll
    for (int off = 1; off < 64; off <<= 1) {
      int y = __shfl_down(x, off);
      if (l + off < 64) x += y;
    }
    if (l == 0) wtot[w] = x;
    __syncthreads();
    int hi = 0;
#pragma unroll
    for (int ww = 0; ww < 4; ++ww) if (ww > w) hi += wtot[ww];
    const int S = x + hi;
    const int total = wtot[0] + wtot[1] + wtot[2] + wtot[3];
    if (total >= TOPK) {
      if (S >= TOPK && S - c < TOPK) sB = t;
      __syncthreads();
      B = sB;
      break;
    }
    __syncthreads();
    lo = m - 2.5f * (float)(2 << iter);
  }
  if (B < 0) B = 0;

  int cc = 0;
#pragma unroll
  for (int r = 0; r < 32; ++r) {
    float s = v[r];
    if (s >= lo) {
      int b = (int)((s - lo) * invw);
      b = (b > 255) ? 255 : b;
      if (b >= B) ++cc;
    }
  }
  {
    int x = cc;
#pragma unroll
    for (int off = 1; off < 64; off <<= 1) {
      int y = __shfl_up(x, off);
      if (l >= off) x += y;
    }
    if (l == 63) wtot[w] = x;
    __syncthreads();
    int lowsum = 0;
#pragma unroll
    for (int ww = 0; ww < 4; ++ww) if (ww < w) lowsum += wtot[ww];
    int base = lowsum + x - cc;
    const int ctotal = wtot[0] + wtot[1] + wtot[2] + wtot[3];
#pragma unroll
    for (int r = 0; r < 32; ++r) {
      float s = v[r];
      if (s >= lo) {
        int b = (int)((s - lo) * invw);
        b = (b > 255) ? 255 : b;
        if (b >= B) {
          if (base < CCAP) candv[base] = s;
          ++base;
        }
      }
    }
    __syncthreads();
    const int L = (ctotal < CCAP) ? ctotal : CCAP;

    if (t == 0) uT = 0xFFFFFFFFu;
    __syncthreads();
    for (int i = t; i < L; i += 256) {
      float vi = candv[i];
      int g = 0;
      for (int j = 0; j < L; ++j) g += (candv[j] > vi) ? 1 : 0;
      if (g <= TOPK - 1) {
        unsigned ub = __float_as_uint(vi);
        unsigned u = (ub & 0x80000000u) ? ~ub : (ub | 0x80000000u);
        atomicMin(&uT, u);
      }
    }
    __syncthreads();
  }
  const unsigned uth = uT;
  const float T = __uint_as_float((uth & 0x80000000u) ? (uth & 0x7FFFFFFFu) : ~uth);

  int myc = 0;
#pragma unroll
  for (int r = 0; r < 32; ++r) myc += (v[r] >= T) ? 1 : 0;
  int x2 = myc;
#pragma unroll
  for (int off = 1; off < 64; off <<= 1) {
    int y = __shfl_up(x2, off);
    if (l >= off) x2 += y;
  }
  if (l == 63) wtot[w] = x2;
  __syncthreads();
  int lowsum2 = 0;
#pragma unroll
  for (int ww = 0; ww < 4; ++ww) if (ww < w) lowsum2 += wtot[ww];
  int base = lowsum2 + x2 - myc;
  const int total2 = wtot[0] + wtot[1] + wtot[2] + wtot[3];
#pragma unroll
  for (int r = 0; r < 32; ++r) {
    if (v[r] >= T) {
      if (base < CAP) {
        pb[base] = __expf(v[r] - m);
        jb[base] = ((r >> 2) * 256 + t) * 4 + (r & 3);
      }
      ++base;
    }
  }
  __syncthreads();
  const int L2 = (total2 < CAP) ? total2 : CAP;

  float ps = 0.0f;
  for (int i = t; i < L2; i += 256) ps += pb[i];
#pragma unroll
  for (int off = 32; off; off >>= 1) ps += __shfl_xor(ps, off);
  if (l == 0) wsum[w] = ps;
  __syncthreads();
  const float inv = 1.0f / (wsum[0] + wsum[1] + wsum[2] + wsum[3]);
  for (int i = t; i < L2; i += 256) {
    wts[(size_t)grow * CAP + i] = pb[i] * inv;
    idx[(size_t)grow * CAP + i] = jb[i];
  }
  if (t == 0) cnt[grow] = L2;
}

// ---------------------------------------------------------------------------
__global__ __launch_bounds__(256)
void sparse_av(const float* __restrict__ V, const float* __restrict__ wts,
               const int* __restrict__ idx, const int* __restrict__ cnt,
               float* __restrict__ out)
{
  __shared__ float wl[CAP];
  __shared__ int   jl[CAP];
  const int t = threadIdx.x;
  const int row = blockIdx.x;
  const int L = cnt[row];
  if (t < CAP && t < L) {
    wl[t] = wts[(size_t)row * CAP + t];
    jl[t] = idx[(size_t)row * CAP + t];
  }
  __syncthreads();
  float acc = 0.0f;
  for (int i = 0; i < L; ++i)
    acc = fmaf(wl[i], V[(size_t)jl[i] * DD + t], acc);
  out[(size_t)row * DD + t] = acc;
}

// ---------------------------------------------------------------------------
extern "C" void kernel_launch(void* const* d_in, const int* in_sizes, int n_in,
                              void* d_out, int out_size, void* d_ws, size_t ws_size,
                              hipStream_t stream)
{
  const float* X    = (const float*)d_in[0];
  const float* Wq   = (const float*)d_in[1];
  const float* bq   = (const float*)d_in[2];
  const float* Wk   = (const float*)d_in[3];
  const float* bk   = (const float*)d_in[4];
  const float* Wv   = (const float*)d_in[5];
  const float* bv   = (const float*)d_in[6];
  const float* temp = (const float*)d_in[7];
  float* out = (float*)d_out;
  float* ws  = (float*)d_ws;

  const size_t avail = ws_size / sizeof(float);

  const size_t szV   = (size_t)NN * DD;          // V f32
  const size_t szHL  = (size_t)NN * 768 / 2;     // f16 hi/lo buf (float units)
  const size_t szWts = (size_t)NN * CAP;
  const size_t szIdx = (size_t)NN * CAP;
  const size_t szCnt = NN;
  const size_t fixed = szV + 2 * szHL + szWts + szIdx + szCnt;

  size_t o = 0;
  float* Vbuf = ws + o; o += szV;
  f16*   Qs   = (f16*)(ws + o); o += szHL;
  f16*   Ks   = (f16*)(ws + o); o += szHL;
  float* wts  = ws + o; o += szWts;
  int*   idxb = (int*)(ws + o); o += szIdx;
  int*   cntb = (int*)(ws + o); o += szCnt;

  if (avail <= fixed + (size_t)128 * NN) return;
  int CR = (int)(((avail - fixed) / NN) / 128) * 128;
  if (CR > CRMAX) CR = CRMAX;       // 64 MB chunk: write->read->overwrite
  if (CR > NN) CR = NN;             // cycle stays L3-resident
  float* Sc = ws + o;

  dim3 blk(256);

  // fused Q/K/V projections (exact f32 math; shared-X 64x64x3 tiles)
  gemm_qkv<<<dim3(NN/64, 4), blk, 0, stream>>>(X, Wq, bq, Wk, bk, Wv, bv,
                                               Qs, Ks, Vbuf);

  for (int r0 = 0; r0 < NN; r0 += CR) {
    const int rows = (NN - r0 < CR) ? (NN - r0) : CR;
    gemm_scores_f16<<<dim3(rows/128, NN/128), blk, 0, stream>>>(
        Qs + (size_t)r0 * 768, Ks, Sc, temp, r0);
    topk_softmax3<<<dim3(rows), blk, 0, stream>>>(Sc, r0, wts, idxb, cntb);
  }

  sparse_av<<<dim3(NN), blk, 0, stream>>>(Vbuf, wts, idxb, cntb, out);
}

// Round 13
// 332.310 us; speedup vs baseline: 1.6459x; 1.1397x over previous
//
#include <hip/hip_runtime.h>
#include <math.h>

#define NN 8192
#define DD 256
#define TOPK 64
#define CAP 96            // survivor capacity per row
#define CCAP 256          // candidate capacity for exact select
#define CRMAX 2048        // score-chunk rows: Sc = 64 MB -> L3-resident
#define NEGVAL (-1000000000.0f)

typedef _Float16 f16;
typedef f16  f16x4 __attribute__((ext_vector_type(4)));
typedef f16  f16x8 __attribute__((ext_vector_type(8)));
typedef float f32x4 __attribute__((ext_vector_type(4)));

// ---------------------------------------------------------------------------
// Fused QKV projection (R11, proven 56us): shared-X 64x64x3 tiles, padded LDS.
// Q,K written as f16 hi/lo score layout ([hi|hi|lo] / [hi|lo|hi]); V f32.
// ---------------------------------------------------------------------------
__global__ __launch_bounds__(256)
void gemm_qkv(const float* __restrict__ X,
              const float* __restrict__ Wq, const float* __restrict__ bq,
              const float* __restrict__ Wk, const float* __restrict__ bk,
              const float* __restrict__ Wv, const float* __restrict__ bv,
              f16* __restrict__ Qs, f16* __restrict__ Ks,
              float* __restrict__ Vf)
{
  __shared__ float As[32][68];
  __shared__ float Bs[3][32][68];
  const int t  = threadIdx.x;
  const int tm = t & 15;
  const int tn = t >> 4;
  const int m0 = blockIdx.x * 64;
  const int n0 = blockIdx.y * 64;

  float acc[3][4][4];
#pragma unroll
  for (int g = 0; g < 3; ++g)
#pragma unroll
    for (int i = 0; i < 4; ++i)
#pragma unroll
      for (int j = 0; j < 4; ++j) acc[g][i][j] = 0.0f;

  for (int k0 = 0; k0 < DD; k0 += 32) {
    __syncthreads();
#pragma unroll
    for (int i = 0; i < 2; ++i) {
      const int slot = t + i * 256;
      const int row  = slot >> 3;
      const int c4   = (slot & 7) << 2;
      float4 av = *(const float4*)(X + (size_t)(m0 + row) * DD + k0 + c4);
      As[c4 + 0][row] = av.x; As[c4 + 1][row] = av.y;
      As[c4 + 2][row] = av.z; As[c4 + 3][row] = av.w;
      float4 q4 = *(const float4*)(Wq + (size_t)(n0 + row) * DD + k0 + c4);
      Bs[0][c4 + 0][row] = q4.x; Bs[0][c4 + 1][row] = q4.y;
      Bs[0][c4 + 2][row] = q4.z; Bs[0][c4 + 3][row] = q4.w;
      float4 k4 = *(const float4*)(Wk + (size_t)(n0 + row) * DD + k0 + c4);
      Bs[1][c4 + 0][row] = k4.x; Bs[1][c4 + 1][row] = k4.y;
      Bs[1][c4 + 2][row] = k4.z; Bs[1][c4 + 3][row] = k4.w;
      float4 v4 = *(const float4*)(Wv + (size_t)(n0 + row) * DD + k0 + c4);
      Bs[2][c4 + 0][row] = v4.x; Bs[2][c4 + 1][row] = v4.y;
      Bs[2][c4 + 2][row] = v4.z; Bs[2][c4 + 3][row] = v4.w;
    }
    __syncthreads();
#pragma unroll
    for (int kk = 0; kk < 32; ++kk) {
      float a[4];
      *(float4*)&a[0] = *(const float4*)&As[kk][tm * 4];
      float b0[4], b1[4], b2[4];
      *(float4*)&b0[0] = *(const float4*)&Bs[0][kk][tn * 4];
      *(float4*)&b1[0] = *(const float4*)&Bs[1][kk][tn * 4];
      *(float4*)&b2[0] = *(const float4*)&Bs[2][kk][tn * 4];
#pragma unroll
      for (int i = 0; i < 4; ++i)
#pragma unroll
        for (int j = 0; j < 4; ++j) {
          acc[0][i][j] = fmaf(a[i], b0[j], acc[0][i][j]);
          acc[1][i][j] = fmaf(a[i], b1[j], acc[1][i][j]);
          acc[2][i][j] = fmaf(a[i], b2[j], acc[2][i][j]);
        }
    }
  }

#pragma unroll
  for (int r = 0; r < 4; ++r) {
    const int grow  = m0 + tm * 4 + r;
    const int gcol0 = n0 + tn * 4;
    {
      f16x4 h4, l4;
#pragma unroll
      for (int c = 0; c < 4; ++c) {
        const float val = acc[0][r][c] + bq[gcol0 + c];
        f16 h = (f16)val;
        h4[c] = h;
        l4[c] = (f16)(val - (float)h);
      }
      f16* base = Qs + (size_t)grow * 768 + gcol0;
      *(f16x4*)(base)       = h4;
      *(f16x4*)(base + 256) = h4;
      *(f16x4*)(base + 512) = l4;
    }
    {
      f16x4 h4, l4;
#pragma unroll
      for (int c = 0; c < 4; ++c) {
        const float val = acc[1][r][c] + bk[gcol0 + c];
        f16 h = (f16)val;
        h4[c] = h;
        l4[c] = (f16)(val - (float)h);
      }
      f16* base = Ks + (size_t)grow * 768 + gcol0;
      *(f16x4*)(base)       = h4;
      *(f16x4*)(base + 256) = l4;
      *(f16x4*)(base + 512) = h4;
    }
    {
      float val[4];
#pragma unroll
      for (int c = 0; c < 4; ++c)
        val[c] = acc[2][r][c] + bv[gcol0 + c];
      *(float4*)(Vf + (size_t)grow * DD + gcol0) =
          make_float4(val[0], val[1], val[2], val[3]);
    }
  }
}

// ---------------------------------------------------------------------------
typedef __attribute__((address_space(1))) const void GV;
typedef __attribute__((address_space(3))) void LV;
__device__ __forceinline__ void gl_lds16(const void* g, void* l) {
  __builtin_amdgcn_global_load_lds((GV*)g, (LV*)l, 16, 0, 0);
}

// ---------------------------------------------------------------------------
// MFMA scores GEMM v4: 256x256 tile, BK=64, 8 waves (2Mx4N), 512 threads.
// 2 LDS dbufs x (A 32KB + B 32KB) = 128KB. Counted-vmcnt depth-1 pipeline:
//   stage(kt+1 -> buf^1); vmcnt(8) [kt done, kt+1 IN FLIGHT across barrier];
//   s_barrier; 4 phases {ds_read, setprio(1), 16 MFMA, setprio(0)}; s_barrier.
// Both-sides XOR swizzle (R4-verified): source granule (l&7)^(l>>3), read
// granule (kk*4+fg)^(fr&7) -> 2-way bank access (free). MFMA order per acc
// is k-ascending == R3 -> bitwise-identical scores.
// ---------------------------------------------------------------------------
__global__ __launch_bounds__(512, 1)
void gemm_scores_f16(const f16* __restrict__ Aq, const f16* __restrict__ Bk,
                     float* __restrict__ C, const float* __restrict__ temp,
                     int rowOff)
{
  __shared__ __align__(16) f16 lds[2][2][256 * 64];   // [dbuf][A/B] = 128 KB

  const int t  = threadIdx.x;          // 0..511
  const int l  = t & 63;
  const int w  = t >> 6;               // wave 0..7
  const int wm = w >> 2;               // M half (128 rows)
  const int wn = w & 3;                // N quarter (64 cols)
  const int m0 = blockIdx.x * 256;
  const int n0 = blockIdx.y * 256;
  const int fr = l & 15;
  const int fg = l >> 4;

  // staging geometry: round j covers rows j*64 + w*8 + (l>>3); lane LDS
  // offset = l*16B; source granule pre-swizzled by row&7 (= l>>3).
  const int srow = w * 8 + (l >> 3);
  const int koff = ((l & 7) ^ (l >> 3)) * 8;   // f16 units, 16B-aligned

  f32x4 acc[8][4];
#pragma unroll
  for (int m = 0; m < 8; ++m)
#pragma unroll
    for (int n = 0; n < 4; ++n) acc[m][n] = (f32x4){0.f, 0.f, 0.f, 0.f};

  auto stage = [&](int d, int kt) {
    const int kb = kt * 64 + koff;
#pragma unroll
    for (int j = 0; j < 4; ++j)
      gl_lds16(Aq + (size_t)(m0 + j * 64 + srow) * 768 + kb,
               &lds[d][0][j * 4096 + w * 512]);
#pragma unroll
    for (int j = 0; j < 4; ++j)
      gl_lds16(Bk + (size_t)(n0 + j * 64 + srow) * 768 + kb,
               &lds[d][1][j * 4096 + w * 512]);
  };

  stage(0, 0);    // prologue: K-tile 0 into buf0 (8 loads in flight)

#pragma unroll 1
  for (int kt = 0; kt < 12; ++kt) {
    const int d = kt & 1;
    if (kt + 1 < 12) {
      stage(d ^ 1, kt + 1);                              // +8 loads
      asm volatile("s_waitcnt vmcnt(8)" ::: "memory");   // kt's 8 done
    } else {
      asm volatile("s_waitcnt vmcnt(0)" ::: "memory");
    }
    __builtin_amdgcn_s_barrier();            // all waves' kt loads landed
    __builtin_amdgcn_sched_barrier(0);

    const f16* Ab = &lds[d][0][0];
    const f16* Bb = &lds[d][1][0];
#pragma unroll
    for (int kk = 0; kk < 2; ++kk) {
      const int g = ((kk * 4 + fg) ^ (fr & 7)) * 8;      // swizzled granule
      f16x8 bf[4];
#pragma unroll
      for (int n = 0; n < 4; ++n)
        bf[n] = *(const f16x8*)&Bb[(wn * 64 + n * 16 + fr) * 64 + g];
#pragma unroll
      for (int mh = 0; mh < 2; ++mh) {
        f16x8 af[4];
#pragma unroll
        for (int i = 0; i < 4; ++i)
          af[i] = *(const f16x8*)&Ab[(wm * 128 + (mh * 4 + i) * 16 + fr) * 64 + g];
        __builtin_amdgcn_s_setprio(1);
#pragma unroll
        for (int i = 0; i < 4; ++i)
#pragma unroll
          for (int n = 0; n < 4; ++n)
            acc[mh * 4 + i][n] = __builtin_amdgcn_mfma_f32_16x16x32_f16(
                af[i], bf[n], acc[mh * 4 + i][n], 0, 0, 0);
        __builtin_amdgcn_s_setprio(0);
      }
    }
    __builtin_amdgcn_sched_barrier(0);
    __builtin_amdgcn_s_barrier();            // buf d free for restage at kt+1
  }

  const float invts = 1.0f / (temp[0] * 16.0f);
#pragma unroll
  for (int m = 0; m < 8; ++m)
#pragma unroll
    for (int n = 0; n < 4; ++n) {
      const int gcol = n0 + wn * 64 + n * 16 + fr;       // C/D: col = lane&15
#pragma unroll
      for (int j = 0; j < 4; ++j) {                      // row = (lane>>4)*4+j
        const int lrow = m0 + wm * 128 + m * 16 + fg * 4 + j;
        float x = acc[m][n][j] * invts;
        if (rowOff + lrow == gcol) x = NEGVAL;
        C[(size_t)lrow * NN + gcol] = x;
      }
    }
}

// ---------------------------------------------------------------------------
// topk_softmax v3 (proven R8): wave-level scans, exact 64th-largest,
// deterministic compaction.
// ---------------------------------------------------------------------------
__global__ __launch_bounds__(256)
void topk_softmax3(const float* __restrict__ Sc, int rowOff,
                   float* __restrict__ wts, int* __restrict__ idx,
                   int* __restrict__ cnt)
{
  __shared__ unsigned hist[256];
  __shared__ float    candv[CCAP];
  __shared__ float    pb[CAP];
  __shared__ int      jb[CAP];
  __shared__ float    wmax[4], wsum[4];
  __shared__ int      wtot[4];
  __shared__ int      sB;
  __shared__ unsigned uT;

  const int t = threadIdx.x;
  const int l = t & 63;
  const int w = t >> 6;
  const int grow = rowOff + blockIdx.x;
  const float* srow = Sc + (size_t)blockIdx.x * NN;

  float v[32];
#pragma unroll
  for (int c = 0; c < 8; ++c) {
    float4 f = *(const float4*)(srow + ((size_t)c * 256 + t) * 4);
    v[c * 4 + 0] = f.x; v[c * 4 + 1] = f.y; v[c * 4 + 2] = f.z; v[c * 4 + 3] = f.w;
  }

  float lm = -3.0e38f;
#pragma unroll
  for (int r = 0; r < 32; ++r) lm = fmaxf(lm, v[r]);
#pragma unroll
  for (int off = 32; off; off >>= 1) lm = fmaxf(lm, __shfl_xor(lm, off));
  if (l == 0) wmax[w] = lm;
  __syncthreads();
  const float m = fmaxf(fmaxf(wmax[0], wmax[1]), fmaxf(wmax[2], wmax[3]));

  float lo = m - 2.5f;
  float invw = 0.0f;
  int B = -1;
  for (int iter = 0; iter < 8; ++iter) {
    hist[t] = 0u;
    __syncthreads();
    invw = 256.0f / (m - lo);
#pragma unroll
    for (int r = 0; r < 32; ++r) {
      float s = v[r];
      if (s >= lo) {
        int b = (int)((s - lo) * invw);
        b = (b > 255) ? 255 : b;
        atomicAdd(&hist[b], 1u);
      }
    }
    __syncthreads();
    const int c = (int)hist[t];
    int x = c;
#pragma unroll
    for (int off = 1; off < 64; off <<= 1) {
      int y = __shfl_down(x, off);
      if (l + off < 64) x += y;
    }
    if (l == 0) wtot[w] = x;
    __syncthreads();
    int hi = 0;
#pragma unroll
    for (int ww = 0; ww < 4; ++ww) if (ww > w) hi += wtot[ww];
    const int S = x + hi;
    const int total = wtot[0] + wtot[1] + wtot[2] + wtot[3];
    if (total >= TOPK) {
      if (S >= TOPK && S - c < TOPK) sB = t;
      __syncthreads();
      B = sB;
      break;
    }
    __syncthreads();
    lo = m - 2.5f * (float)(2 << iter);
  }
  if (B < 0) B = 0;

  int cc = 0;
#pragma unroll
  for (int r = 0; r < 32; ++r) {
    float s = v[r];
    if (s >= lo) {
      int b = (int)((s - lo) * invw);
      b = (b > 255) ? 255 : b;
      if (b >= B) ++cc;
    }
  }
  {
    int x = cc;
#pragma unroll
    for (int off = 1; off < 64; off <<= 1) {
      int y = __shfl_up(x, off);
      if (l >= off) x += y;
    }
    if (l == 63) wtot[w] = x;
    __syncthreads();
    int lowsum = 0;
#pragma unroll
    for (int ww = 0; ww < 4; ++ww) if (ww < w) lowsum += wtot[ww];
    int base = lowsum + x - cc;
    const int ctotal = wtot[0] + wtot[1] + wtot[2] + wtot[3];
#pragma unroll
    for (int r = 0; r < 32; ++r) {
      float s = v[r];
      if (s >= lo) {
        int b = (int)((s - lo) * invw);
        b = (b > 255) ? 255 : b;
        if (b >= B) {
          if (base < CCAP) candv[base] = s;
          ++base;
        }
      }
    }
    __syncthreads();
    const int L = (ctotal < CCAP) ? ctotal : CCAP;

    if (t == 0) uT = 0xFFFFFFFFu;
    __syncthreads();
    for (int i = t; i < L; i += 256) {
      float vi = candv[i];
      int g = 0;
      for (int j = 0; j < L; ++j) g += (candv[j] > vi) ? 1 : 0;
      if (g <= TOPK - 1) {
        unsigned ub = __float_as_uint(vi);
        unsigned u = (ub & 0x80000000u) ? ~ub : (ub | 0x80000000u);
        atomicMin(&uT, u);
      }
    }
    __syncthreads();
  }
  const unsigned uth = uT;
  const float T = __uint_as_float((uth & 0x80000000u) ? (uth & 0x7FFFFFFFu) : ~uth);

  int myc = 0;
#pragma unroll
  for (int r = 0; r < 32; ++r) myc += (v[r] >= T) ? 1 : 0;
  int x2 = myc;
#pragma unroll
  for (int off = 1; off < 64; off <<= 1) {
    int y = __shfl_up(x2, off);
    if (l >= off) x2 += y;
  }
  if (l == 63) wtot[w] = x2;
  __syncthreads();
  int lowsum2 = 0;
#pragma unroll
  for (int ww = 0; ww < 4; ++ww) if (ww < w) lowsum2 += wtot[ww];
  int base = lowsum2 + x2 - myc;
  const int total2 = wtot[0] + wtot[1] + wtot[2] + wtot[3];
#pragma unroll
  for (int r = 0; r < 32; ++r) {
    if (v[r] >= T) {
      if (base < CAP) {
        pb[base] = __expf(v[r] - m);
        jb[base] = ((r >> 2) * 256 + t) * 4 + (r & 3);
      }
      ++base;
    }
  }
  __syncthreads();
  const int L2 = (total2 < CAP) ? total2 : CAP;

  float ps = 0.0f;
  for (int i = t; i < L2; i += 256) ps += pb[i];
#pragma unroll
  for (int off = 32; off; off >>= 1) ps += __shfl_xor(ps, off);
  if (l == 0) wsum[w] = ps;
  __syncthreads();
  const float inv = 1.0f / (wsum[0] + wsum[1] + wsum[2] + wsum[3]);
  for (int i = t; i < L2; i += 256) {
    wts[(size_t)grow * CAP + i] = pb[i] * inv;
    idx[(size_t)grow * CAP + i] = jb[i];
  }
  if (t == 0) cnt[grow] = L2;
}

// ---------------------------------------------------------------------------
__global__ __launch_bounds__(256)
void sparse_av(const float* __restrict__ V, const float* __restrict__ wts,
               const int* __restrict__ idx, const int* __restrict__ cnt,
               float* __restrict__ out)
{
  __shared__ float wl[CAP];
  __shared__ int   jl[CAP];
  const int t = threadIdx.x;
  const int row = blockIdx.x;
  const int L = cnt[row];
  if (t < CAP && t < L) {
    wl[t] = wts[(size_t)row * CAP + t];
    jl[t] = idx[(size_t)row * CAP + t];
  }
  __syncthreads();
  float acc = 0.0f;
  for (int i = 0; i < L; ++i)
    acc = fmaf(wl[i], V[(size_t)jl[i] * DD + t], acc);
  out[(size_t)row * DD + t] = acc;
}

// ---------------------------------------------------------------------------
extern "C" void kernel_launch(void* const* d_in, const int* in_sizes, int n_in,
                              void* d_out, int out_size, void* d_ws, size_t ws_size,
                              hipStream_t stream)
{
  const float* X    = (const float*)d_in[0];
  const float* Wq   = (const float*)d_in[1];
  const float* bq   = (const float*)d_in[2];
  const float* Wk   = (const float*)d_in[3];
  const float* bk   = (const float*)d_in[4];
  const float* Wv   = (const float*)d_in[5];
  const float* bv   = (const float*)d_in[6];
  const float* temp = (const float*)d_in[7];
  float* out = (float*)d_out;
  float* ws  = (float*)d_ws;

  const size_t avail = ws_size / sizeof(float);

  const size_t szV   = (size_t)NN * DD;          // V f32
  const size_t szHL  = (size_t)NN * 768 / 2;     // f16 hi/lo buf (float units)
  const size_t szWts = (size_t)NN * CAP;
  const size_t szIdx = (size_t)NN * CAP;
  const size_t szCnt = NN;
  const size_t fixed = szV + 2 * szHL + szWts + szIdx + szCnt;

  size_t o = 0;
  float* Vbuf = ws + o; o += szV;
  f16*   Qs   = (f16*)(ws + o); o += szHL;
  f16*   Ks   = (f16*)(ws + o); o += szHL;
  float* wts  = ws + o; o += szWts;
  int*   idxb = (int*)(ws + o); o += szIdx;
  int*   cntb = (int*)(ws + o); o += szCnt;

  if (avail <= fixed + (size_t)256 * NN) return;
  int CR = (int)(((avail - fixed) / NN) / 256) * 256;   // multiple of 256 now
  if (CR > CRMAX) CR = CRMAX;       // 64 MB chunk: write->read->overwrite
  if (CR > NN) CR = NN;             // cycle stays L3-resident
  float* Sc = ws + o;

  dim3 blk(256);
  dim3 blk2(512);

  // fused Q/K/V projections (exact f32 math; shared-X 64x64x3 tiles)
  gemm_qkv<<<dim3(NN/64, 4), blk, 0, stream>>>(X, Wq, bq, Wk, bk, Wv, bv,
                                               Qs, Ks, Vbuf);

  for (int r0 = 0; r0 < NN; r0 += CR) {
    const int rows = (NN - r0 < CR) ? (NN - r0) : CR;
    gemm_scores_f16<<<dim3(rows/256, NN/256), blk2, 0, stream>>>(
        Qs + (size_t)r0 * 768, Ks, Sc, temp, r0);
    topk_softmax3<<<dim3(rows), blk, 0, stream>>>(Sc, r0, wts, idxb, cntb);
  }

  sparse_av<<<dim3(NN), blk, 0, stream>>>(Vbuf, wts, idxb, cntb, out);
}